// Round 5
// baseline (805.213 us; speedup 1.0000x reference)
//
#include <hip/hip_runtime.h>
#include <hip/hip_bf16.h>
#include <math.h>

#define N_NODES 50000
#define N_EDGES 800000
#define HCH 256      // H*HID concat width
#define NHEAD 4
#define HIDC 64
#define NCLS 349
#define F_IN 128

typedef short short8 __attribute__((ext_vector_type(8)));
typedef float floatx4 __attribute__((ext_vector_type(4)));

// ---------------- edge_index storage-width detection ----------------
__global__ void k_detect(const unsigned* ei, int* flag) {
    if (blockIdx.x == 0 && threadIdx.x == 0) {
        int i64 = 1;
        for (int e = 0; e < 64; e++)
            if (ei[2 * e + 1] != 0u) { i64 = 0; break; }
        *flag = i64;
    }
}

__device__ __forceinline__ void edge_sd(const int* ei, int e, int i64, int& s, int& d) {
    if (i64) {
        const long long* p = (const long long*)ei;
        s = (int)p[e]; d = (int)p[N_EDGES + e];
    } else {
        s = ei[e]; d = ei[N_EDGES + e];
    }
}

// ---------------- CSR build (by dst) ----------------
__global__ void k_deg(const int* ei, const int* flag, int* deg) {
    int e = blockIdx.x * 256 + threadIdx.x;
    if (e >= N_EDGES) return;
    int s, d; edge_sd(ei, e, *flag, s, d);
    atomicAdd(&deg[d], 1);
}

__global__ void k_scan(const int* __restrict__ deg, int* __restrict__ rowptr) {
    __shared__ int sums[1024];
    int t = threadIdx.x;
    const int CH = (N_NODES + 1023) / 1024;  // 49
    int beg = t * CH;
    int end = min(beg + CH, N_NODES);
    int s = 0;
    for (int i = beg; i < end; i++) s += deg[i];
    sums[t] = s;
    __syncthreads();
    for (int off = 1; off < 1024; off <<= 1) {
        int v = (t >= off) ? sums[t - off] : 0;
        __syncthreads();
        sums[t] += v;
        __syncthreads();
    }
    int excl = (t == 0) ? 0 : sums[t - 1];
    for (int i = beg; i < end; i++) { rowptr[i] = excl; excl += deg[i]; }
    if (t == 1023) rowptr[N_NODES] = sums[1023];
}

__global__ void k_fill(const int* ei, const int* flag, const int* __restrict__ rowptr,
                       int* cursor, int* __restrict__ esrc) {
    int e = blockIdx.x * 256 + threadIdx.x;
    if (e >= N_EDGES) return;
    int s, d; edge_sd(ei, e, *flag, s, d);
    int pos = atomicAdd(&cursor[d], 1);
    esrc[rowptr[d] + pos] = s;
}

// ---------------- attention-score folding ----------------
__global__ void k_wtilde(const float* __restrict__ ws, const float* __restrict__ wd,
                         const float* __restrict__ atts, const float* __restrict__ attd,
                         float* __restrict__ wt, int d) {
    int id = blockIdx.x * 256 + threadIdx.x;
    if (id >= d * 8) return;
    int j = id & 7, k = id >> 3;
    const float* w = (j < 4) ? ws : wd;
    const float* at = (j < 4) ? atts : attd;
    int h = j & 3;
    float s = 0.f;
    for (int c = 0; c < HIDC; c++) s += w[k * HCH + h * HIDC + c] * at[h * HIDC + c];
    wt[k * 8 + j] = s;
}

__global__ void k_attn(const float* __restrict__ x, const float* __restrict__ wt,
                       float* __restrict__ a, int d) {
    int n = blockIdx.x;
    int lane = threadIdx.x;
    float p[8] = {0, 0, 0, 0, 0, 0, 0, 0};
    for (int t = 0; t < d; t += 64) {
        float xv = x[(size_t)n * d + t + lane];
        const float* w = &wt[(t + lane) * 8];
        #pragma unroll
        for (int j = 0; j < 8; j++) p[j] += xv * w[j];
    }
    #pragma unroll
    for (int j = 0; j < 8; j++) {
        float v = p[j];
        for (int off = 32; off >= 1; off >>= 1) v += __shfl_xor(v, off, 64);
        p[j] = v;
    }
    if (lane == 0) {
        #pragma unroll
        for (int j = 0; j < 8; j++) a[(size_t)n * 8 + j] = p[j];
    }
}

// ---------------- split fp32 -> bf16 hi + bf16 lo ----------------
__device__ __forceinline__ void bsplit(float v, unsigned short& h, unsigned short& l) {
    __hip_bfloat16 bh = __float2bfloat16(v);
    float hv = __bfloat162float(bh);
    __hip_bfloat16 bl = __float2bfloat16(v - hv);
    h = *(unsigned short*)&bh;
    l = *(unsigned short*)&bl;
}

__global__ void k_split(const float* __restrict__ A, unsigned short* __restrict__ Hh,
                        unsigned short* __restrict__ Hl, size_t n) {
    for (size_t i = (size_t)blockIdx.x * 256 + threadIdx.x; i < n;
         i += (size_t)gridDim.x * 256) {
        unsigned short h, l;
        bsplit(A[i], h, l);
        Hh[i] = h; Hl[i] = l;
    }
}

// build transposed+split weight: Bt[c][k] from W = [ws | lw] columns (c<256: ws, else lw)
__global__ void k_wcat_t(const float* __restrict__ ws, const float* __restrict__ lw,
                         int K, unsigned short* __restrict__ Bh, unsigned short* __restrict__ Bl) {
    int id = blockIdx.x * 256 + threadIdx.x;
    if (id >= 512 * K) return;
    int c = id / K, k = id % K;
    float v = (c < 256) ? ws[(size_t)k * 256 + c] : lw[(size_t)k * 256 + (c - 256)];
    unsigned short h, l;
    bsplit(v, h, l);
    Bh[(size_t)c * K + k] = h;
    Bl[(size_t)c * K + k] = l;
}

// transposed+split fcw: Bt[384][256], pad cols (>=349) zeroed
__global__ void k_fcw_t(const float* __restrict__ fcw, int K,
                        unsigned short* __restrict__ Bh, unsigned short* __restrict__ Bl) {
    int id = blockIdx.x * 256 + threadIdx.x;
    if (id >= 384 * K) return;
    int c = id / K, k = id % K;
    float v = (c < NCLS) ? fcw[(size_t)k * NCLS + c] : 0.f;
    unsigned short h, l;
    bsplit(v, h, l);
    Bh[(size_t)c * K + k] = h;
    Bl[(size_t)c * K + k] = l;
}

// ---------------- split-bf16 MFMA GEMM ----------------
// C ~= Ah*Bh + Al*Bh + Ah*Bl (split-bf16 ~ fp32 precision).
// Epilogue: if C != null -> f32 C[r*ldc+c] (+bias). Else cols<256 -> bf16 xsb,
// cols>=256 -> bf16 linbb.
__global__ __launch_bounds__(256) void k_gemm3(
    const unsigned short* __restrict__ Ah, const unsigned short* __restrict__ Al,
    const unsigned short* __restrict__ Bh, const unsigned short* __restrict__ Bl,
    float* __restrict__ C, int ldc, __hip_bfloat16* __restrict__ xsb,
    __hip_bfloat16* __restrict__ linbb,
    const float* __restrict__ bias, int M, int K, int Nc) {
    __shared__ unsigned short sAh[128 * 40];
    __shared__ unsigned short sAl[128 * 40];
    __shared__ unsigned short sBh[128 * 40];
    __shared__ unsigned short sBl[128 * 40];
    int tid = threadIdx.x;
    int lane = tid & 63, wave = tid >> 6;
    int wm = wave >> 1, wn = wave & 1;
    int row0 = blockIdx.x * 128, col0 = blockIdx.y * 128;
    floatx4 acc[4][4] = {};
    int sr = tid >> 1;
    int sc = (tid & 1) * 2;
    int kc = lane >> 4;
    int fr = lane & 15;
    for (int k0 = 0; k0 < K; k0 += 32) {
        int4 z = {0, 0, 0, 0};
        int4 vh0 = z, vh1 = z, vl0 = z, vl1 = z;
        int gr = row0 + sr;
        if (gr < M) {
            const unsigned short* pa = Ah + (size_t)gr * K + k0 + sc * 8;
            const unsigned short* pl = Al + (size_t)gr * K + k0 + sc * 8;
            vh0 = *(const int4*)(pa);
            vh1 = *(const int4*)(pa + 8);
            vl0 = *(const int4*)(pl);
            vl1 = *(const int4*)(pl + 8);
        }
        *(int4*)((char*)sAh + sr * 80 + sc * 16) = vh0;
        *(int4*)((char*)sAh + sr * 80 + sc * 16 + 16) = vh1;
        *(int4*)((char*)sAl + sr * 80 + sc * 16) = vl0;
        *(int4*)((char*)sAl + sr * 80 + sc * 16 + 16) = vl1;
        const unsigned short* pb = Bh + (size_t)(col0 + sr) * K + k0 + sc * 8;
        const unsigned short* pbl = Bl + (size_t)(col0 + sr) * K + k0 + sc * 8;
        *(int4*)((char*)sBh + sr * 80 + sc * 16) = *(const int4*)(pb);
        *(int4*)((char*)sBh + sr * 80 + sc * 16 + 16) = *(const int4*)(pb + 8);
        *(int4*)((char*)sBl + sr * 80 + sc * 16) = *(const int4*)(pbl);
        *(int4*)((char*)sBl + sr * 80 + sc * 16 + 16) = *(const int4*)(pbl + 8);
        __syncthreads();
        short8 fah[4], fal[4], fbh[4], fbl[4];
        #pragma unroll
        for (int i = 0; i < 4; i++) {
            int ar = wm * 64 + i * 16 + fr;
            fah[i] = *(const short8*)((const char*)sAh + ar * 80 + kc * 16);
            fal[i] = *(const short8*)((const char*)sAl + ar * 80 + kc * 16);
            int bc = wn * 64 + i * 16 + fr;
            fbh[i] = *(const short8*)((const char*)sBh + bc * 80 + kc * 16);
            fbl[i] = *(const short8*)((const char*)sBl + bc * 80 + kc * 16);
        }
        #pragma unroll
        for (int i = 0; i < 4; i++)
            #pragma unroll
            for (int j = 0; j < 4; j++) {
                acc[i][j] = __builtin_amdgcn_mfma_f32_16x16x32_bf16(fah[i], fbh[j], acc[i][j], 0, 0, 0);
                acc[i][j] = __builtin_amdgcn_mfma_f32_16x16x32_bf16(fal[i], fbh[j], acc[i][j], 0, 0, 0);
                acc[i][j] = __builtin_amdgcn_mfma_f32_16x16x32_bf16(fah[i], fbl[j], acc[i][j], 0, 0, 0);
            }
        __syncthreads();
    }
    #pragma unroll
    for (int i = 0; i < 4; i++) {
        #pragma unroll
        for (int j = 0; j < 4; j++) {
            int c = col0 + wn * 64 + j * 16 + fr;
            if (c >= Nc) continue;
            float bv = bias ? bias[c] : 0.f;
            #pragma unroll
            for (int q = 0; q < 4; q++) {
                int r = row0 + wm * 64 + i * 16 + (lane >> 4) * 4 + q;
                if (r >= M) continue;
                float val = acc[i][j][q] + bv;
                if (C) C[(size_t)r * ldc + c] = val;
                else if (c < 256) xsb[(size_t)r * 256 + c] = __float2bfloat16(val);
                else linbb[(size_t)r * 256 + (c - 256)] = __float2bfloat16(val);
            }
        }
    }
}

// ---------------- fused CSR gather-aggregation ----------------
// R4 fix: VALU-bound -> stage per-(edge,head) ev once in LDS (1 exp per (e,h)
// instead of 64 redundant), consume via broadcast LDS reads + 8x batched gather.
#define LEAKY_EXP(vv) __expf(((vv) > 0.f) ? (vv) : 0.2f * (vv))

__global__ __launch_bounds__(256) void k_agg(
    const __hip_bfloat16* __restrict__ xsb,
    const __hip_bfloat16* __restrict__ linb, const float* __restrict__ a,
    const int* __restrict__ rowptr, const int* __restrict__ esrc,
    const float* __restrict__ bg, const float* __restrict__ lb,
    float* __restrict__ hout) {
    __shared__ float sev[4][64];
    __shared__ int sidx[64];
    int n = blockIdx.x;
    int c = threadIdx.x;
    int h = c >> 6;     // head of this thread (also its staging head slot)
    int u = c & 63;     // edge slot within chunk for staging
    float ad = a[(size_t)n * 8 + 4 + h];
    int beg = rowptr[n], end = rowptr[n + 1];
    float acc = 0.f, dsum = 0.f;
    for (int k0 = beg; k0 < end; k0 += 64) {
        int mcnt = min(64, end - k0);
        if (u < mcnt) {
            int s = esrc[k0 + u];
            sev[h][u] = LEAKY_EXP(a[(size_t)s * 8 + h] + ad);
            if (h == 0) sidx[u] = s;
        }
        __syncthreads();
        int u2 = 0;
        for (; u2 + 8 <= mcnt; u2 += 8) {
            int s[8]; float ev[8];
            #pragma unroll
            for (int q = 0; q < 8; q++) { s[q] = sidx[u2 + q]; ev[q] = sev[h][u2 + q]; }
            float mm[8];
            #pragma unroll
            for (int q = 0; q < 8; q++)
                mm[q] = __bfloat162float(xsb[(size_t)s[q] * 256 + c]);
            #pragma unroll
            for (int q = 0; q < 8; q++) { acc += mm[q] * ev[q]; dsum += ev[q]; }
        }
        for (; u2 < mcnt; u2++) {
            int s = sidx[u2];
            float ev = sev[h][u2];
            acc += __bfloat162float(xsb[(size_t)s * 256 + c]) * ev;
            dsum += ev;
        }
        __syncthreads();
    }
    hout[(size_t)n * 256 + c] = acc / (dsum + 1e-16f) + bg[c] +
                                __bfloat162float(linb[(size_t)n * 256 + c]) + lb[c];
}

// ---------------- BatchNorm (batch stats) + ReLU (+ fused bf16 split) ----------------
__global__ void k_bnstats(const float* __restrict__ hbuf, float* __restrict__ bnsum,
                          float* __restrict__ bnsq) {
    int c = threadIdx.x;
    float s = 0.f, q = 0.f;
    for (int r = blockIdx.x; r < N_NODES; r += gridDim.x) {
        float v = hbuf[(size_t)r * 256 + c];
        s += v; q += v * v;
    }
    atomicAdd(&bnsum[c], s);
    atomicAdd(&bnsq[c], q);
}

__global__ void k_bnfin(const float* __restrict__ bnsum, const float* __restrict__ bnsq,
                        float* __restrict__ mu, float* __restrict__ rs) {
    int c = threadIdx.x;
    float m = bnsum[c] / (float)N_NODES;
    float v = bnsq[c] / (float)N_NODES - m * m;
    mu[c] = m;
    rs[c] = rsqrtf(v + 1e-5f);
}

__global__ void k_bnapply(float* __restrict__ hbuf, unsigned short* __restrict__ hh,
                          unsigned short* __restrict__ hl, const float* __restrict__ mu,
                          const float* __restrict__ rs, const float* __restrict__ g,
                          const float* __restrict__ b) {
    size_t tot = (size_t)N_NODES * 256;
    for (size_t i = (size_t)blockIdx.x * 256 + threadIdx.x; i < tot;
         i += (size_t)gridDim.x * 256) {
        int c = (int)(i & 255);
        float v = (hbuf[i] - mu[c]) * rs[c] * g[c] + b[c];
        v = v > 0.f ? v : 0.f;
        hbuf[i] = v;
        unsigned short h16, l16;
        bsplit(v, h16, l16);
        hh[i] = h16; hl[i] = l16;
    }
}

// ---------------- host ----------------
extern "C" void kernel_launch(void* const* d_in, const int* in_sizes, int n_in,
                              void* d_out, int out_size, void* d_ws, size_t ws_size,
                              hipStream_t stream) {
    const float* x     = (const float*)d_in[0];
    const int*   ei    = (const int*)d_in[1];
    const float* ws0   = (const float*)d_in[2];
    const float* wd0   = (const float*)d_in[3];
    const float* atts0 = (const float*)d_in[4];
    const float* attd0 = (const float*)d_in[5];
    const float* bg0   = (const float*)d_in[6];
    const float* lw0   = (const float*)d_in[7];
    const float* lb0   = (const float*)d_in[8];
    const float* g0    = (const float*)d_in[9];
    const float* b0    = (const float*)d_in[10];
    const float* ws1   = (const float*)d_in[11];
    const float* wd1   = (const float*)d_in[12];
    const float* atts1 = (const float*)d_in[13];
    const float* attd1 = (const float*)d_in[14];
    const float* bg1   = (const float*)d_in[15];
    const float* lw1   = (const float*)d_in[16];
    const float* lb1   = (const float*)d_in[17];
    const float* g1    = (const float*)d_in[18];
    const float* b1    = (const float*)d_in[19];
    const float* fcw   = (const float*)d_in[20];
    const float* fcb   = (const float*)d_in[21];
    float* out = (float*)d_out;

    char* p = (char*)d_ws;
    auto alloc = [&](size_t bytes) -> char* {
        char* r = p;
        p += (bytes + 255) & ~(size_t)255;
        return r;
    };
    __hip_bfloat16* xsb  = (__hip_bfloat16*)alloc((size_t)N_NODES * 256 * 2);
    __hip_bfloat16* linb = (__hip_bfloat16*)alloc((size_t)N_NODES * 256 * 2);
    float* hbuf   = (float*)alloc((size_t)N_NODES * 256 * 4);
    unsigned short* hh = (unsigned short*)alloc((size_t)N_NODES * 256 * 2);
    unsigned short* hl = (unsigned short*)alloc((size_t)N_NODES * 256 * 2);
    unsigned short* xh = hh;   // overlay: x-split dead after gemm L0, hh/hl written at bnapply0
    unsigned short* xl = hh + (size_t)N_NODES * 128;
    float* a      = (float*)alloc((size_t)N_NODES * 8 * 4);
    int*   esrc   = (int*)alloc((size_t)N_EDGES * 4);
    int*   rowptr = (int*)alloc((size_t)(N_NODES + 1) * 4);
    unsigned short* w0h = (unsigned short*)alloc((size_t)512 * 128 * 2);
    unsigned short* w0l = (unsigned short*)alloc((size_t)512 * 128 * 2);
    unsigned short* w1h = (unsigned short*)alloc((size_t)512 * 256 * 2);
    unsigned short* w1l = (unsigned short*)alloc((size_t)512 * 256 * 2);
    unsigned short* fch = (unsigned short*)alloc((size_t)384 * 256 * 2);
    unsigned short* fcl = (unsigned short*)alloc((size_t)384 * 256 * 2);
    float* wtil   = (float*)alloc((size_t)256 * 8 * 4);
    float* mu     = (float*)alloc(256 * 4);
    float* rs     = (float*)alloc(256 * 4);
    int*   flag   = (int*)alloc(256);
    size_t zr_bytes = (size_t)N_NODES * 4 * 2 + 4 * 256 * 4;
    char* zbase = alloc(zr_bytes);
    int*   deg    = (int*)zbase;
    int*   cursor = deg + N_NODES;
    float* bnsum0 = (float*)(cursor + N_NODES);
    float* bnsq0  = bnsum0 + 256;
    float* bnsum1 = bnsq0 + 256;
    float* bnsq1  = bnsum1 + 256;

    hipMemsetAsync(zbase, 0, zr_bytes, stream);

    const int EB = (N_EDGES + 255) / 256;
    const int RB = (N_NODES + 127) / 128;

    k_detect<<<1, 1, 0, stream>>>((const unsigned*)ei, flag);
    k_deg<<<EB, 256, 0, stream>>>(ei, flag, deg);
    k_scan<<<1, 1024, 0, stream>>>(deg, rowptr);
    k_fill<<<EB, 256, 0, stream>>>(ei, flag, rowptr, cursor, esrc);

    // weight prep
    k_wcat_t<<<(512 * 128 + 255) / 256, 256, 0, stream>>>(ws0, lw0, 128, w0h, w0l);
    k_wcat_t<<<(512 * 256 + 255) / 256, 256, 0, stream>>>(ws1, lw1, 256, w1h, w1l);
    k_fcw_t<<<(384 * 256 + 255) / 256, 256, 0, stream>>>(fcw, 256, fch, fcl);
    k_wtilde<<<(128 * 8 + 255) / 256, 256, 0, stream>>>(ws0, wd0, atts0, attd0, wtil, 128);

    // ---- layer 0 (d = 128) ----
    k_attn<<<N_NODES, 64, 0, stream>>>(x, wtil, a, 128);
    k_split<<<2048, 256, 0, stream>>>(x, xh, xl, (size_t)N_NODES * 128);
    k_gemm3<<<dim3(RB, 4), 256, 0, stream>>>(xh, xl, w0h, w0l, nullptr, 0, xsb, linb,
                                             nullptr, N_NODES, 128, 512);
    k_agg<<<N_NODES, 256, 0, stream>>>(xsb, linb, a, rowptr, esrc, bg0, lb0, hbuf);
    k_bnstats<<<256, 256, 0, stream>>>(hbuf, bnsum0, bnsq0);
    k_bnfin<<<1, 256, 0, stream>>>(bnsum0, bnsq0, mu, rs);
    k_bnapply<<<2048, 256, 0, stream>>>(hbuf, hh, hl, mu, rs, g0, b0);

    // ---- layer 1 (d = 256) ----
    k_wtilde<<<(256 * 8 + 255) / 256, 256, 0, stream>>>(ws1, wd1, atts1, attd1, wtil, 256);
    k_attn<<<N_NODES, 64, 0, stream>>>(hbuf, wtil, a, 256);
    k_gemm3<<<dim3(RB, 4), 256, 0, stream>>>(hh, hl, w1h, w1l, nullptr, 0, xsb, linb,
                                             nullptr, N_NODES, 256, 512);
    k_agg<<<N_NODES, 256, 0, stream>>>(xsb, linb, a, rowptr, esrc, bg1, lb1, hbuf);
    k_bnstats<<<256, 256, 0, stream>>>(hbuf, bnsum1, bnsq1);
    k_bnfin<<<1, 256, 0, stream>>>(bnsum1, bnsq1, mu, rs);
    k_bnapply<<<2048, 256, 0, stream>>>(hbuf, hh, hl, mu, rs, g1, b1);

    // ---- final FC ----
    k_gemm3<<<dim3(RB, 3), 256, 0, stream>>>(hh, hl, fch, fcl, out, NCLS, nullptr, nullptr,
                                             fcb, N_NODES, 256, NCLS);
}

// Round 6
// 712.730 us; speedup vs baseline: 1.1298x; 1.1298x over previous
//
#include <hip/hip_runtime.h>
#include <hip/hip_bf16.h>
#include <math.h>

#define N_NODES 50000
#define N_EDGES 800000
#define HCH 256      // H*HID concat width
#define NHEAD 4
#define HIDC 64
#define NCLS 349
#define F_IN 128

typedef short short8 __attribute__((ext_vector_type(8)));
typedef float floatx4 __attribute__((ext_vector_type(4)));

// ---------------- edge_index storage-width detection ----------------
__global__ void k_detect(const unsigned* ei, int* flag) {
    if (blockIdx.x == 0 && threadIdx.x == 0) {
        int i64 = 1;
        for (int e = 0; e < 64; e++)
            if (ei[2 * e + 1] != 0u) { i64 = 0; break; }
        *flag = i64;
    }
}

__device__ __forceinline__ void edge_sd(const int* ei, int e, int i64, int& s, int& d) {
    if (i64) {
        const long long* p = (const long long*)ei;
        s = (int)p[e]; d = (int)p[N_EDGES + e];
    } else {
        s = ei[e]; d = ei[N_EDGES + e];
    }
}

// ---------------- CSR build (by dst) ----------------
__global__ void k_deg(const int* ei, const int* flag, int* deg) {
    int e = blockIdx.x * 256 + threadIdx.x;
    if (e >= N_EDGES) return;
    int s, d; edge_sd(ei, e, *flag, s, d);
    atomicAdd(&deg[d], 1);
}

__global__ void k_scan(const int* __restrict__ deg, int* __restrict__ rowptr) {
    __shared__ int sums[1024];
    int t = threadIdx.x;
    const int CH = (N_NODES + 1023) / 1024;  // 49
    int beg = t * CH;
    int end = min(beg + CH, N_NODES);
    int s = 0;
    for (int i = beg; i < end; i++) s += deg[i];
    sums[t] = s;
    __syncthreads();
    for (int off = 1; off < 1024; off <<= 1) {
        int v = (t >= off) ? sums[t - off] : 0;
        __syncthreads();
        sums[t] += v;
        __syncthreads();
    }
    int excl = (t == 0) ? 0 : sums[t - 1];
    for (int i = beg; i < end; i++) { rowptr[i] = excl; excl += deg[i]; }
    if (t == 1023) rowptr[N_NODES] = sums[1023];
}

__global__ void k_fill(const int* ei, const int* flag, const int* __restrict__ rowptr,
                       int* cursor, int* __restrict__ esrc) {
    int e = blockIdx.x * 256 + threadIdx.x;
    if (e >= N_EDGES) return;
    int s, d; edge_sd(ei, e, *flag, s, d);
    int pos = atomicAdd(&cursor[d], 1);
    esrc[rowptr[d] + pos] = s;
}

// ---------------- attention-score folding ----------------
__global__ void k_wtilde(const float* __restrict__ ws, const float* __restrict__ wd,
                         const float* __restrict__ atts, const float* __restrict__ attd,
                         float* __restrict__ wt, int d) {
    int id = blockIdx.x * 256 + threadIdx.x;
    if (id >= d * 8) return;
    int j = id & 7, k = id >> 3;
    const float* w = (j < 4) ? ws : wd;
    const float* at = (j < 4) ? atts : attd;
    int h = j & 3;
    float s = 0.f;
    for (int c = 0; c < HIDC; c++) s += w[k * HCH + h * HIDC + c] * at[h * HIDC + c];
    wt[k * 8 + j] = s;
}

// ---------------- split fp32 -> bf16 hi + bf16 lo ----------------
__device__ __forceinline__ void bsplit(float v, unsigned short& h, unsigned short& l) {
    __hip_bfloat16 bh = __float2bfloat16(v);
    float hv = __bfloat162float(bh);
    __hip_bfloat16 bl = __float2bfloat16(v - hv);
    h = *(unsigned short*)&bh;
    l = *(unsigned short*)&bl;
}

// fused weight, transposed+split: Bt[c][k], c in [0,640)
// c<256: ws col; c<512: lw col; c<520: wtilde col (attention); else 0 pad.
__global__ void k_wcat_t(const float* __restrict__ ws, const float* __restrict__ lw,
                         const float* __restrict__ wtil, int K,
                         unsigned short* __restrict__ Bh, unsigned short* __restrict__ Bl) {
    int id = blockIdx.x * 256 + threadIdx.x;
    if (id >= 640 * K) return;
    int c = id / K, k = id % K;
    float v;
    if (c < 256) v = ws[(size_t)k * 256 + c];
    else if (c < 512) v = lw[(size_t)k * 256 + (c - 256)];
    else if (c < 520) v = wtil[(size_t)k * 8 + (c - 512)];
    else v = 0.f;
    unsigned short h, l;
    bsplit(v, h, l);
    Bh[(size_t)c * K + k] = h;
    Bl[(size_t)c * K + k] = l;
}

// transposed+split fcw: Bt[384][256], pad cols (>=349) zeroed
__global__ void k_fcw_t(const float* __restrict__ fcw, int K,
                        unsigned short* __restrict__ Bh, unsigned short* __restrict__ Bl) {
    int id = blockIdx.x * 256 + threadIdx.x;
    if (id >= 384 * K) return;
    int c = id / K, k = id % K;
    float v = (c < NCLS) ? fcw[(size_t)k * NCLS + c] : 0.f;
    unsigned short h, l;
    bsplit(v, h, l);
    Bh[(size_t)c * K + k] = h;
    Bl[(size_t)c * K + k] = l;
}

// ---------------- split-bf16 MFMA GEMM ----------------
// C ~= Ah*Bh + Al*Bh + Ah*Bl (split-bf16 ~ fp32 precision).
// A source: Af32 (f32, split in-staging) if non-null, else (Ah,Al) pre-split.
// Epilogue: if C -> f32 C[r*ldc+c]+bias; else c<256 -> bf16 xsb,
// c<512 -> bf16 linbb, c<520 -> f32 aout[r*8+(c-512)] (attention scores).
__global__ __launch_bounds__(256) void k_gemm3(
    const float* __restrict__ Af32,
    const unsigned short* __restrict__ Ah, const unsigned short* __restrict__ Al,
    const unsigned short* __restrict__ Bh, const unsigned short* __restrict__ Bl,
    float* __restrict__ C, int ldc, __hip_bfloat16* __restrict__ xsb,
    __hip_bfloat16* __restrict__ linbb, float* __restrict__ aout,
    const float* __restrict__ bias, int M, int K, int Nc) {
    __shared__ unsigned short sAh[128 * 40];
    __shared__ unsigned short sAl[128 * 40];
    __shared__ unsigned short sBh[128 * 40];
    __shared__ unsigned short sBl[128 * 40];
    int tid = threadIdx.x;
    int lane = tid & 63, wave = tid >> 6;
    int wm = wave >> 1, wn = wave & 1;
    int row0 = blockIdx.x * 128, col0 = blockIdx.y * 128;
    floatx4 acc[4][4] = {};
    int sr = tid >> 1;
    int sc = (tid & 1) * 2;
    int kc = lane >> 4;
    int fr = lane & 15;
    for (int k0 = 0; k0 < K; k0 += 32) {
        int4 z = {0, 0, 0, 0};
        int4 vh0 = z, vh1 = z, vl0 = z, vl1 = z;
        int gr = row0 + sr;
        if (gr < M) {
            if (Af32) {
                const float* px = Af32 + (size_t)gr * K + k0 + sc * 8;
                float4 f0 = *(const float4*)(px);
                float4 f1 = *(const float4*)(px + 4);
                float4 f2 = *(const float4*)(px + 8);
                float4 f3 = *(const float4*)(px + 12);
                float xv[16] = {f0.x, f0.y, f0.z, f0.w, f1.x, f1.y, f1.z, f1.w,
                                f2.x, f2.y, f2.z, f2.w, f3.x, f3.y, f3.z, f3.w};
                union { unsigned short us[8]; int4 v; } uh0, uh1, ul0, ul1;
                #pragma unroll
                for (int q = 0; q < 8; q++) {
                    bsplit(xv[q], uh0.us[q], ul0.us[q]);
                    bsplit(xv[q + 8], uh1.us[q], ul1.us[q]);
                }
                vh0 = uh0.v; vh1 = uh1.v; vl0 = ul0.v; vl1 = ul1.v;
            } else {
                const unsigned short* pa = Ah + (size_t)gr * K + k0 + sc * 8;
                const unsigned short* pl = Al + (size_t)gr * K + k0 + sc * 8;
                vh0 = *(const int4*)(pa);
                vh1 = *(const int4*)(pa + 8);
                vl0 = *(const int4*)(pl);
                vl1 = *(const int4*)(pl + 8);
            }
        }
        *(int4*)((char*)sAh + sr * 80 + sc * 16) = vh0;
        *(int4*)((char*)sAh + sr * 80 + sc * 16 + 16) = vh1;
        *(int4*)((char*)sAl + sr * 80 + sc * 16) = vl0;
        *(int4*)((char*)sAl + sr * 80 + sc * 16 + 16) = vl1;
        const unsigned short* pb = Bh + (size_t)(col0 + sr) * K + k0 + sc * 8;
        const unsigned short* pbl = Bl + (size_t)(col0 + sr) * K + k0 + sc * 8;
        *(int4*)((char*)sBh + sr * 80 + sc * 16) = *(const int4*)(pb);
        *(int4*)((char*)sBh + sr * 80 + sc * 16 + 16) = *(const int4*)(pb + 8);
        *(int4*)((char*)sBl + sr * 80 + sc * 16) = *(const int4*)(pbl);
        *(int4*)((char*)sBl + sr * 80 + sc * 16 + 16) = *(const int4*)(pbl + 8);
        __syncthreads();
        short8 fah[4], fal[4], fbh[4], fbl[4];
        #pragma unroll
        for (int i = 0; i < 4; i++) {
            int ar = wm * 64 + i * 16 + fr;
            fah[i] = *(const short8*)((const char*)sAh + ar * 80 + kc * 16);
            fal[i] = *(const short8*)((const char*)sAl + ar * 80 + kc * 16);
            int bc = wn * 64 + i * 16 + fr;
            fbh[i] = *(const short8*)((const char*)sBh + bc * 80 + kc * 16);
            fbl[i] = *(const short8*)((const char*)sBl + bc * 80 + kc * 16);
        }
        #pragma unroll
        for (int i = 0; i < 4; i++)
            #pragma unroll
            for (int j = 0; j < 4; j++) {
                acc[i][j] = __builtin_amdgcn_mfma_f32_16x16x32_bf16(fah[i], fbh[j], acc[i][j], 0, 0, 0);
                acc[i][j] = __builtin_amdgcn_mfma_f32_16x16x32_bf16(fal[i], fbh[j], acc[i][j], 0, 0, 0);
                acc[i][j] = __builtin_amdgcn_mfma_f32_16x16x32_bf16(fah[i], fbl[j], acc[i][j], 0, 0, 0);
            }
        __syncthreads();
    }
    #pragma unroll
    for (int i = 0; i < 4; i++) {
        #pragma unroll
        for (int j = 0; j < 4; j++) {
            int c = col0 + wn * 64 + j * 16 + fr;
            if (c >= Nc) continue;
            float bv = bias ? bias[c] : 0.f;
            #pragma unroll
            for (int q = 0; q < 4; q++) {
                int r = row0 + wm * 64 + i * 16 + (lane >> 4) * 4 + q;
                if (r >= M) continue;
                float val = acc[i][j][q] + bv;
                if (C) C[(size_t)r * ldc + c] = val;
                else if (c < 256) xsb[(size_t)r * 256 + c] = __float2bfloat16(val);
                else if (c < 512) linbb[(size_t)r * 256 + (c - 256)] = __float2bfloat16(val);
                else aout[(size_t)r * 8 + (c - 512)] = val;
            }
        }
    }
}

// ---------------- fused CSR gather-aggregation (R4 ILP version) ----------------
#define LEAKY_EXP(vv) __expf(((vv) > 0.f) ? (vv) : 0.2f * (vv))

__global__ __launch_bounds__(256) void k_agg(
    const __hip_bfloat16* __restrict__ xsb,
    const __hip_bfloat16* __restrict__ linb, const float* __restrict__ a,
    const int* __restrict__ rowptr, const int* __restrict__ esrc,
    const float* __restrict__ bg, const float* __restrict__ lb,
    float* __restrict__ hout) {
    int n = blockIdx.x;
    int c = threadIdx.x;
    int h = c >> 6;
    float ad = a[(size_t)n * 8 + 4 + h];
    int beg = rowptr[n], end = rowptr[n + 1];
    float acc = 0.f, dsum = 0.f;
    int k = beg;
    for (; k + 8 <= end; k += 8) {
        int s[8];
        #pragma unroll
        for (int u = 0; u < 8; u++) s[u] = esrc[k + u];
        float av[8];
        #pragma unroll
        for (int u = 0; u < 8; u++) av[u] = a[(size_t)s[u] * 8 + h];
        float m[8];
        #pragma unroll
        for (int u = 0; u < 8; u++)
            m[u] = __bfloat162float(xsb[(size_t)s[u] * 256 + c]);
        #pragma unroll
        for (int u = 0; u < 8; u++) {
            float ev = LEAKY_EXP(av[u] + ad);
            acc += m[u] * ev;
            dsum += ev;
        }
    }
    for (; k + 4 <= end; k += 4) {
        int s[4];
        #pragma unroll
        for (int u = 0; u < 4; u++) s[u] = esrc[k + u];
        float av[4];
        #pragma unroll
        for (int u = 0; u < 4; u++) av[u] = a[(size_t)s[u] * 8 + h];
        float m[4];
        #pragma unroll
        for (int u = 0; u < 4; u++)
            m[u] = __bfloat162float(xsb[(size_t)s[u] * 256 + c]);
        #pragma unroll
        for (int u = 0; u < 4; u++) {
            float ev = LEAKY_EXP(av[u] + ad);
            acc += m[u] * ev;
            dsum += ev;
        }
    }
    for (; k < end; k++) {
        int s = esrc[k];
        float ev = LEAKY_EXP(a[(size_t)s * 8 + h] + ad);
        acc += __bfloat162float(xsb[(size_t)s * 256 + c]) * ev;
        dsum += ev;
    }
    hout[(size_t)n * 256 + c] = acc / (dsum + 1e-16f) + bg[c] +
                                __bfloat162float(linb[(size_t)n * 256 + c]) + lb[c];
}

// ---------------- BatchNorm ----------------
__global__ void k_bnstats(const float* __restrict__ hbuf, float* __restrict__ bnsum,
                          float* __restrict__ bnsq) {
    int c = threadIdx.x;
    float s = 0.f, q = 0.f;
    for (int r = blockIdx.x; r < N_NODES; r += gridDim.x) {
        float v = hbuf[(size_t)r * 256 + c];
        s += v; q += v * v;
    }
    atomicAdd(&bnsum[c], s);
    atomicAdd(&bnsq[c], q);
}

// BN finalize (per-block redundant) + affine + ReLU + bf16 split; hh/hl only.
__global__ __launch_bounds__(256) void k_bnapply(
    const float* __restrict__ hbuf, unsigned short* __restrict__ hh,
    unsigned short* __restrict__ hl, const float* __restrict__ bnsum,
    const float* __restrict__ bnsq, const float* __restrict__ g,
    const float* __restrict__ b) {
    __shared__ float smu[256], srs[256];
    int t = threadIdx.x;
    {
        float m = bnsum[t] / (float)N_NODES;
        float v = bnsq[t] / (float)N_NODES - m * m;
        smu[t] = m;
        srs[t] = rsqrtf(v + 1e-5f);
    }
    __syncthreads();
    size_t tot = (size_t)N_NODES * 256;
    for (size_t i = (size_t)blockIdx.x * 256 + t; i < tot;
         i += (size_t)gridDim.x * 256) {
        int c = (int)(i & 255);
        float v = (hbuf[i] - smu[c]) * srs[c] * g[c] + b[c];
        v = v > 0.f ? v : 0.f;
        unsigned short h16, l16;
        bsplit(v, h16, l16);
        hh[i] = h16; hl[i] = l16;
    }
}

// ---------------- host ----------------
extern "C" void kernel_launch(void* const* d_in, const int* in_sizes, int n_in,
                              void* d_out, int out_size, void* d_ws, size_t ws_size,
                              hipStream_t stream) {
    const float* x     = (const float*)d_in[0];
    const int*   ei    = (const int*)d_in[1];
    const float* ws0   = (const float*)d_in[2];
    const float* wd0   = (const float*)d_in[3];
    const float* atts0 = (const float*)d_in[4];
    const float* attd0 = (const float*)d_in[5];
    const float* bg0   = (const float*)d_in[6];
    const float* lw0   = (const float*)d_in[7];
    const float* lb0   = (const float*)d_in[8];
    const float* g0    = (const float*)d_in[9];
    const float* b0    = (const float*)d_in[10];
    const float* ws1   = (const float*)d_in[11];
    const float* wd1   = (const float*)d_in[12];
    const float* atts1 = (const float*)d_in[13];
    const float* attd1 = (const float*)d_in[14];
    const float* bg1   = (const float*)d_in[15];
    const float* lw1   = (const float*)d_in[16];
    const float* lb1   = (const float*)d_in[17];
    const float* g1    = (const float*)d_in[18];
    const float* b1    = (const float*)d_in[19];
    const float* fcw   = (const float*)d_in[20];
    const float* fcb   = (const float*)d_in[21];
    float* out = (float*)d_out;

    char* p = (char*)d_ws;
    auto alloc = [&](size_t bytes) -> char* {
        char* r = p;
        p += (bytes + 255) & ~(size_t)255;
        return r;
    };
    __hip_bfloat16* xsb  = (__hip_bfloat16*)alloc((size_t)N_NODES * 256 * 2);
    __hip_bfloat16* linb = (__hip_bfloat16*)alloc((size_t)N_NODES * 256 * 2);
    float* hbuf   = (float*)alloc((size_t)N_NODES * 256 * 4);
    unsigned short* hh = (unsigned short*)alloc((size_t)N_NODES * 256 * 2);
    unsigned short* hl = (unsigned short*)alloc((size_t)N_NODES * 256 * 2);
    float* a      = (float*)alloc((size_t)N_NODES * 8 * 4);
    int*   esrc   = (int*)alloc((size_t)N_EDGES * 4);
    int*   rowptr = (int*)alloc((size_t)(N_NODES + 1) * 4);
    unsigned short* w0h = (unsigned short*)alloc((size_t)640 * 128 * 2);
    unsigned short* w0l = (unsigned short*)alloc((size_t)640 * 128 * 2);
    unsigned short* w1h = (unsigned short*)alloc((size_t)640 * 256 * 2);
    unsigned short* w1l = (unsigned short*)alloc((size_t)640 * 256 * 2);
    unsigned short* fch = (unsigned short*)alloc((size_t)384 * 256 * 2);
    unsigned short* fcl = (unsigned short*)alloc((size_t)384 * 256 * 2);
    float* wtil   = (float*)alloc((size_t)256 * 8 * 4);
    int*   flag   = (int*)alloc(256);
    size_t zr_bytes = (size_t)N_NODES * 4 * 2 + 4 * 256 * 4;
    char* zbase = alloc(zr_bytes);
    int*   deg    = (int*)zbase;
    int*   cursor = deg + N_NODES;
    float* bnsum0 = (float*)(cursor + N_NODES);
    float* bnsq0  = bnsum0 + 256;
    float* bnsum1 = bnsq0 + 256;
    float* bnsq1  = bnsum1 + 256;

    hipMemsetAsync(zbase, 0, zr_bytes, stream);

    const int EB = (N_EDGES + 255) / 256;
    const int RB = (N_NODES + 127) / 128;

    k_detect<<<1, 1, 0, stream>>>((const unsigned*)ei, flag);
    k_deg<<<EB, 256, 0, stream>>>(ei, flag, deg);
    k_scan<<<1, 1024, 0, stream>>>(deg, rowptr);
    k_fill<<<EB, 256, 0, stream>>>(ei, flag, rowptr, cursor, esrc);

    // weight prep (wtil buffer reused sequentially; stream is serial)
    k_wtilde<<<(128 * 8 + 255) / 256, 256, 0, stream>>>(ws0, wd0, atts0, attd0, wtil, 128);
    k_wcat_t<<<(640 * 128 + 255) / 256, 256, 0, stream>>>(ws0, lw0, wtil, 128, w0h, w0l);
    k_wtilde<<<(256 * 8 + 255) / 256, 256, 0, stream>>>(ws1, wd1, atts1, attd1, wtil, 256);
    k_wcat_t<<<(640 * 256 + 255) / 256, 256, 0, stream>>>(ws1, lw1, wtil, 256, w1h, w1l);
    k_fcw_t<<<(384 * 256 + 255) / 256, 256, 0, stream>>>(fcw, 256, fch, fcl);

    // ---- layer 0 (d = 128): gemm emits xs(bf16) | lin(bf16) | attention a ----
    k_gemm3<<<dim3(RB, 5), 256, 0, stream>>>(x, nullptr, nullptr, w0h, w0l,
                                             nullptr, 0, xsb, linb, a,
                                             nullptr, N_NODES, 128, 520);
    k_agg<<<N_NODES, 256, 0, stream>>>(xsb, linb, a, rowptr, esrc, bg0, lb0, hbuf);
    k_bnstats<<<256, 256, 0, stream>>>(hbuf, bnsum0, bnsq0);
    k_bnapply<<<2048, 256, 0, stream>>>(hbuf, hh, hl, bnsum0, bnsq0, g0, b0);

    // ---- layer 1 (d = 256) ----
    k_gemm3<<<dim3(RB, 5), 256, 0, stream>>>(nullptr, hh, hl, w1h, w1l,
                                             nullptr, 0, xsb, linb, a,
                                             nullptr, N_NODES, 256, 520);
    k_agg<<<N_NODES, 256, 0, stream>>>(xsb, linb, a, rowptr, esrc, bg1, lb1, hbuf);
    k_bnstats<<<256, 256, 0, stream>>>(hbuf, bnsum1, bnsq1);
    k_bnapply<<<2048, 256, 0, stream>>>(hbuf, hh, hl, bnsum1, bnsq1, g1, b1);

    // ---- final FC ----
    k_gemm3<<<dim3(RB, 3), 256, 0, stream>>>(nullptr, hh, hl, fch, fcl,
                                             out, NCLS, nullptr, nullptr, nullptr,
                                             fcb, N_NODES, 256, NCLS);
}

// Round 7
// 680.508 us; speedup vs baseline: 1.1833x; 1.0474x over previous
//
#include <hip/hip_runtime.h>
#include <hip/hip_bf16.h>
#include <math.h>

#define N_NODES 50000
#define N_EDGES 800000
#define HCH 256      // H*HID concat width
#define NHEAD 4
#define HIDC 64
#define NCLS 349
#define F_IN 128

typedef short short8 __attribute__((ext_vector_type(8)));
typedef float floatx4 __attribute__((ext_vector_type(4)));

// ---------------- edge_index storage-width detection ----------------
__global__ void k_detect(const unsigned* ei, int* flag) {
    if (blockIdx.x == 0 && threadIdx.x == 0) {
        int i64 = 1;
        for (int e = 0; e < 64; e++)
            if (ei[2 * e + 1] != 0u) { i64 = 0; break; }
        *flag = i64;
    }
}

__device__ __forceinline__ void edge_sd(const int* ei, int e, int i64, int& s, int& d) {
    if (i64) {
        const long long* p = (const long long*)ei;
        s = (int)p[e]; d = (int)p[N_EDGES + e];
    } else {
        s = ei[e]; d = ei[N_EDGES + e];
    }
}

// ---------------- CSR build (by dst) ----------------
__global__ void k_deg(const int* ei, const int* flag, int* deg) {
    int e = blockIdx.x * 256 + threadIdx.x;
    if (e >= N_EDGES) return;
    int s, d; edge_sd(ei, e, *flag, s, d);
    atomicAdd(&deg[d], 1);
}

__global__ void k_scan(const int* __restrict__ deg, int* __restrict__ rowptr) {
    __shared__ int sums[1024];
    int t = threadIdx.x;
    const int CH = (N_NODES + 1023) / 1024;  // 49
    int beg = t * CH;
    int end = min(beg + CH, N_NODES);
    int s = 0;
    for (int i = beg; i < end; i++) s += deg[i];
    sums[t] = s;
    __syncthreads();
    for (int off = 1; off < 1024; off <<= 1) {
        int v = (t >= off) ? sums[t - off] : 0;
        __syncthreads();
        sums[t] += v;
        __syncthreads();
    }
    int excl = (t == 0) ? 0 : sums[t - 1];
    for (int i = beg; i < end; i++) { rowptr[i] = excl; excl += deg[i]; }
    if (t == 1023) rowptr[N_NODES] = sums[1023];
}

__global__ void k_fill(const int* ei, const int* flag, const int* __restrict__ rowptr,
                       int* cursor, int* __restrict__ esrc) {
    int e = blockIdx.x * 256 + threadIdx.x;
    if (e >= N_EDGES) return;
    int s, d; edge_sd(ei, e, *flag, s, d);
    int pos = atomicAdd(&cursor[d], 1);
    esrc[rowptr[d] + pos] = s;
}

// ---------------- attention-score folding ----------------
__global__ void k_wtilde(const float* __restrict__ ws, const float* __restrict__ wd,
                         const float* __restrict__ atts, const float* __restrict__ attd,
                         float* __restrict__ wt, int d) {
    int id = blockIdx.x * 256 + threadIdx.x;
    if (id >= d * 8) return;
    int j = id & 7, k = id >> 3;
    const float* w = (j < 4) ? ws : wd;
    const float* at = (j < 4) ? atts : attd;
    int h = j & 3;
    float s = 0.f;
    for (int c = 0; c < HIDC; c++) s += w[k * HCH + h * HIDC + c] * at[h * HIDC + c];
    wt[k * 8 + j] = s;
}

// ---------------- bf16 helpers ----------------
__device__ __forceinline__ unsigned short b16(float v) {
    __hip_bfloat16 t = __float2bfloat16(v);
    return *(unsigned short*)&t;
}

__device__ __forceinline__ void bsplit(float v, unsigned short& h, unsigned short& l) {
    __hip_bfloat16 bh = __float2bfloat16(v);
    float hv = __bfloat162float(bh);
    __hip_bfloat16 bl = __float2bfloat16(v - hv);
    h = *(unsigned short*)&bh;
    l = *(unsigned short*)&bl;
}

// fused weight, transposed+split: Bt[c][k], c in [0,640)
// c<256: ws col; c<512: lw col; c<520: wtilde col (attention); else 0 pad.
__global__ void k_wcat_t(const float* __restrict__ ws, const float* __restrict__ lw,
                         const float* __restrict__ wtil, int K,
                         unsigned short* __restrict__ Bh, unsigned short* __restrict__ Bl) {
    int id = blockIdx.x * 256 + threadIdx.x;
    if (id >= 640 * K) return;
    int c = id / K, k = id % K;
    float v;
    if (c < 256) v = ws[(size_t)k * 256 + c];
    else if (c < 512) v = lw[(size_t)k * 256 + (c - 256)];
    else if (c < 520) v = wtil[(size_t)k * 8 + (c - 512)];
    else v = 0.f;
    unsigned short h, l;
    bsplit(v, h, l);
    Bh[(size_t)c * K + k] = h;
    Bl[(size_t)c * K + k] = l;
}

// transposed+split fcw: Bt[384][256], pad cols (>=349) zeroed
__global__ void k_fcw_t(const float* __restrict__ fcw, int K,
                        unsigned short* __restrict__ Bh, unsigned short* __restrict__ Bl) {
    int id = blockIdx.x * 256 + threadIdx.x;
    if (id >= 384 * K) return;
    int c = id / K, k = id % K;
    float v = (c < NCLS) ? fcw[(size_t)k * NCLS + c] : 0.f;
    unsigned short h, l;
    bsplit(v, h, l);
    Bh[(size_t)c * K + k] = h;
    Bl[(size_t)c * K + k] = l;
}

// ---------------- 2-product MFMA GEMM: C ~= Ah*Bh + Ah*Bl ----------------
// Activations bf16 (A: f32 rounded in staging, or bf16 direct); weights split.
// Tile 128x128, BK=32, 4 waves each 64x64.
// Epilogue: if C -> f32 C[r*ldc+c]+bias; else c<256 -> bf16 xsb,
// c<512 -> bf16 linbb, c<520 -> f32 aout[r*8+(c-512)] (attention scores).
__global__ __launch_bounds__(256) void k_gemm2(
    const float* __restrict__ Af32, const __hip_bfloat16* __restrict__ Ab,
    const unsigned short* __restrict__ Bh, const unsigned short* __restrict__ Bl,
    float* __restrict__ C, int ldc, __hip_bfloat16* __restrict__ xsb,
    __hip_bfloat16* __restrict__ linbb, float* __restrict__ aout,
    const float* __restrict__ bias, int M, int K, int Nc) {
    __shared__ unsigned short sA[128 * 40];
    __shared__ unsigned short sBh[128 * 40];
    __shared__ unsigned short sBl[128 * 40];
    int tid = threadIdx.x;
    int lane = tid & 63, wave = tid >> 6;
    int wm = wave >> 1, wn = wave & 1;
    int row0 = blockIdx.x * 128, col0 = blockIdx.y * 128;
    floatx4 acc[4][4] = {};
    int sr = tid >> 1;
    int sc = (tid & 1) * 2;
    int kc = lane >> 4;
    int fr = lane & 15;
    for (int k0 = 0; k0 < K; k0 += 32) {
        int4 z = {0, 0, 0, 0};
        int4 va0 = z, va1 = z;
        int gr = row0 + sr;
        if (gr < M) {
            if (Af32) {
                const float* px = Af32 + (size_t)gr * K + k0 + sc * 8;
                float4 f0 = *(const float4*)(px);
                float4 f1 = *(const float4*)(px + 4);
                float4 f2 = *(const float4*)(px + 8);
                float4 f3 = *(const float4*)(px + 12);
                float xv[16] = {f0.x, f0.y, f0.z, f0.w, f1.x, f1.y, f1.z, f1.w,
                                f2.x, f2.y, f2.z, f2.w, f3.x, f3.y, f3.z, f3.w};
                union { unsigned short us[8]; int4 v; } u0, u1;
                #pragma unroll
                for (int q = 0; q < 8; q++) {
                    u0.us[q] = b16(xv[q]);
                    u1.us[q] = b16(xv[q + 8]);
                }
                va0 = u0.v; va1 = u1.v;
            } else {
                const __hip_bfloat16* pa = Ab + (size_t)gr * K + k0 + sc * 8;
                va0 = *(const int4*)(pa);
                va1 = *(const int4*)(pa + 8);
            }
        }
        *(int4*)((char*)sA + sr * 80 + sc * 16) = va0;
        *(int4*)((char*)sA + sr * 80 + sc * 16 + 16) = va1;
        const unsigned short* pb = Bh + (size_t)(col0 + sr) * K + k0 + sc * 8;
        const unsigned short* pbl = Bl + (size_t)(col0 + sr) * K + k0 + sc * 8;
        *(int4*)((char*)sBh + sr * 80 + sc * 16) = *(const int4*)(pb);
        *(int4*)((char*)sBh + sr * 80 + sc * 16 + 16) = *(const int4*)(pb + 8);
        *(int4*)((char*)sBl + sr * 80 + sc * 16) = *(const int4*)(pbl);
        *(int4*)((char*)sBl + sr * 80 + sc * 16 + 16) = *(const int4*)(pbl + 8);
        __syncthreads();
        short8 fah[4], fbh[4], fbl[4];
        #pragma unroll
        for (int i = 0; i < 4; i++) {
            int ar = wm * 64 + i * 16 + fr;
            fah[i] = *(const short8*)((const char*)sA + ar * 80 + kc * 16);
            int bc = wn * 64 + i * 16 + fr;
            fbh[i] = *(const short8*)((const char*)sBh + bc * 80 + kc * 16);
            fbl[i] = *(const short8*)((const char*)sBl + bc * 80 + kc * 16);
        }
        #pragma unroll
        for (int i = 0; i < 4; i++)
            #pragma unroll
            for (int j = 0; j < 4; j++) {
                acc[i][j] = __builtin_amdgcn_mfma_f32_16x16x32_bf16(fah[i], fbh[j], acc[i][j], 0, 0, 0);
                acc[i][j] = __builtin_amdgcn_mfma_f32_16x16x32_bf16(fah[i], fbl[j], acc[i][j], 0, 0, 0);
            }
        __syncthreads();
    }
    #pragma unroll
    for (int i = 0; i < 4; i++) {
        #pragma unroll
        for (int j = 0; j < 4; j++) {
            int c = col0 + wn * 64 + j * 16 + fr;
            if (c >= Nc) continue;
            float bv = bias ? bias[c] : 0.f;
            #pragma unroll
            for (int q = 0; q < 4; q++) {
                int r = row0 + wm * 64 + i * 16 + (lane >> 4) * 4 + q;
                if (r >= M) continue;
                float val = acc[i][j][q] + bv;
                if (C) C[(size_t)r * ldc + c] = val;
                else if (c < 256) xsb[(size_t)r * 256 + c] = __float2bfloat16(val);
                else if (c < 512) linbb[(size_t)r * 256 + (c - 256)] = __float2bfloat16(val);
                else aout[(size_t)r * 8 + (c - 512)] = val;
            }
        }
    }
}

// ---------------- fused CSR gather-aggregation ----------------
// R6 fix: ev computed once per (edge,head) per wave via shfl broadcast (lane
// u computes edge lane&7's exp; no barriers, no idle staging lanes), keeping
// the 8x batched-gather ILP. Output bf16.
#define LEAKY_EXP(vv) __expf(((vv) > 0.f) ? (vv) : 0.2f * (vv))

__global__ __launch_bounds__(256) void k_agg(
    const __hip_bfloat16* __restrict__ xsb,
    const __hip_bfloat16* __restrict__ linb, const float* __restrict__ a,
    const int* __restrict__ rowptr, const int* __restrict__ esrc,
    const float* __restrict__ bg, const float* __restrict__ lb,
    __hip_bfloat16* __restrict__ hout) {
    int n = blockIdx.x;
    int c = threadIdx.x;
    int h = c >> 6;
    int lane = c & 63;
    float ad = a[(size_t)n * 8 + 4 + h];
    int beg = rowptr[n], end = rowptr[n + 1];
    float acc = 0.f, dsum = 0.f;
    int k = beg;
    for (; k + 8 <= end; k += 8) {
        int s[8];
        #pragma unroll
        for (int u = 0; u < 8; u++) s[u] = esrc[k + u];
        // each lane computes exp for edge (lane&7) only; broadcast via shfl
        float myev = LEAKY_EXP(a[(size_t)s[lane & 7] * 8 + h] + ad);
        float m[8];
        #pragma unroll
        for (int u = 0; u < 8; u++)
            m[u] = __bfloat162float(xsb[(size_t)s[u] * 256 + c]);
        #pragma unroll
        for (int u = 0; u < 8; u++) {
            float ev = __shfl(myev, u, 64);
            acc += m[u] * ev;
            dsum += ev;
        }
    }
    for (; k < end; k++) {
        int s = esrc[k];
        float ev = LEAKY_EXP(a[(size_t)s * 8 + h] + ad);
        acc += __bfloat162float(xsb[(size_t)s * 256 + c]) * ev;
        dsum += ev;
    }
    float v = acc / (dsum + 1e-16f) + bg[c] +
              __bfloat162float(linb[(size_t)n * 256 + c]) + lb[c];
    hout[(size_t)n * 256 + c] = __float2bfloat16(v);
}

// ---------------- BatchNorm (batch stats from bf16 h) ----------------
__global__ void k_bnstats(const __hip_bfloat16* __restrict__ hb,
                          float* __restrict__ bnsum, float* __restrict__ bnsq) {
    int c = threadIdx.x;
    float s = 0.f, q = 0.f;
    for (int r = blockIdx.x; r < N_NODES; r += gridDim.x) {
        float v = __bfloat162float(hb[(size_t)r * 256 + c]);
        s += v; q += v * v;
    }
    atomicAdd(&bnsum[c], s);
    atomicAdd(&bnsq[c], q);
}

// BN finalize (per-block redundant) + affine + ReLU -> bf16 hpost.
__global__ __launch_bounds__(256) void k_bnapply(
    const __hip_bfloat16* __restrict__ hb, __hip_bfloat16* __restrict__ hpost,
    const float* __restrict__ bnsum, const float* __restrict__ bnsq,
    const float* __restrict__ g, const float* __restrict__ b) {
    __shared__ float sA[256], sB[256];
    int t = threadIdx.x;
    {
        float m = bnsum[t] / (float)N_NODES;
        float v = bnsq[t] / (float)N_NODES - m * m;
        float rs = rsqrtf(v + 1e-5f) * g[t];
        sA[t] = rs;
        sB[t] = b[t] - m * rs;
    }
    __syncthreads();
    size_t tot = (size_t)N_NODES * 256;
    for (size_t i = (size_t)blockIdx.x * 256 + t; i < tot;
         i += (size_t)gridDim.x * 256) {
        int c = (int)(i & 255);
        float v = __bfloat162float(hb[i]) * sA[c] + sB[c];
        v = v > 0.f ? v : 0.f;
        hpost[i] = __float2bfloat16(v);
    }
}

// ---------------- host ----------------
extern "C" void kernel_launch(void* const* d_in, const int* in_sizes, int n_in,
                              void* d_out, int out_size, void* d_ws, size_t ws_size,
                              hipStream_t stream) {
    const float* x     = (const float*)d_in[0];
    const int*   ei    = (const int*)d_in[1];
    const float* ws0   = (const float*)d_in[2];
    const float* wd0   = (const float*)d_in[3];
    const float* atts0 = (const float*)d_in[4];
    const float* attd0 = (const float*)d_in[5];
    const float* bg0   = (const float*)d_in[6];
    const float* lw0   = (const float*)d_in[7];
    const float* lb0   = (const float*)d_in[8];
    const float* g0    = (const float*)d_in[9];
    const float* b0    = (const float*)d_in[10];
    const float* ws1   = (const float*)d_in[11];
    const float* wd1   = (const float*)d_in[12];
    const float* atts1 = (const float*)d_in[13];
    const float* attd1 = (const float*)d_in[14];
    const float* bg1   = (const float*)d_in[15];
    const float* lw1   = (const float*)d_in[16];
    const float* lb1   = (const float*)d_in[17];
    const float* g1    = (const float*)d_in[18];
    const float* b1    = (const float*)d_in[19];
    const float* fcw   = (const float*)d_in[20];
    const float* fcb   = (const float*)d_in[21];
    float* out = (float*)d_out;

    char* p = (char*)d_ws;
    auto alloc = [&](size_t bytes) -> char* {
        char* r = p;
        p += (bytes + 255) & ~(size_t)255;
        return r;
    };
    __hip_bfloat16* xsb   = (__hip_bfloat16*)alloc((size_t)N_NODES * 256 * 2);
    __hip_bfloat16* linb  = (__hip_bfloat16*)alloc((size_t)N_NODES * 256 * 2);
    __hip_bfloat16* hb    = (__hip_bfloat16*)alloc((size_t)N_NODES * 256 * 2);
    __hip_bfloat16* hpost = (__hip_bfloat16*)alloc((size_t)N_NODES * 256 * 2);
    float* a      = (float*)alloc((size_t)N_NODES * 8 * 4);
    int*   esrc   = (int*)alloc((size_t)N_EDGES * 4);
    int*   rowptr = (int*)alloc((size_t)(N_NODES + 1) * 4);
    unsigned short* w0h = (unsigned short*)alloc((size_t)640 * 128 * 2);
    unsigned short* w0l = (unsigned short*)alloc((size_t)640 * 128 * 2);
    unsigned short* w1h = (unsigned short*)alloc((size_t)640 * 256 * 2);
    unsigned short* w1l = (unsigned short*)alloc((size_t)640 * 256 * 2);
    unsigned short* fch = (unsigned short*)alloc((size_t)384 * 256 * 2);
    unsigned short* fcl = (unsigned short*)alloc((size_t)384 * 256 * 2);
    float* wtil   = (float*)alloc((size_t)256 * 8 * 4);
    int*   flag   = (int*)alloc(256);
    size_t zr_bytes = (size_t)N_NODES * 4 * 2 + 4 * 256 * 4;
    char* zbase = alloc(zr_bytes);
    int*   deg    = (int*)zbase;
    int*   cursor = deg + N_NODES;
    float* bnsum0 = (float*)(cursor + N_NODES);
    float* bnsq0  = bnsum0 + 256;
    float* bnsum1 = bnsq0 + 256;
    float* bnsq1  = bnsum1 + 256;

    hipMemsetAsync(zbase, 0, zr_bytes, stream);

    const int EB = (N_EDGES + 255) / 256;
    const int RB = (N_NODES + 127) / 128;

    k_detect<<<1, 1, 0, stream>>>((const unsigned*)ei, flag);
    k_deg<<<EB, 256, 0, stream>>>(ei, flag, deg);
    k_scan<<<1, 1024, 0, stream>>>(deg, rowptr);
    k_fill<<<EB, 256, 0, stream>>>(ei, flag, rowptr, cursor, esrc);

    // weight prep (wtil buffer reused sequentially; stream is serial)
    k_wtilde<<<(128 * 8 + 255) / 256, 256, 0, stream>>>(ws0, wd0, atts0, attd0, wtil, 128);
    k_wcat_t<<<(640 * 128 + 255) / 256, 256, 0, stream>>>(ws0, lw0, wtil, 128, w0h, w0l);
    k_wtilde<<<(256 * 8 + 255) / 256, 256, 0, stream>>>(ws1, wd1, atts1, attd1, wtil, 256);
    k_wcat_t<<<(640 * 256 + 255) / 256, 256, 0, stream>>>(ws1, lw1, wtil, 256, w1h, w1l);
    k_fcw_t<<<(384 * 256 + 255) / 256, 256, 0, stream>>>(fcw, 256, fch, fcl);

    // ---- layer 0 (d = 128): gemm emits xs(bf16) | lin(bf16) | attention a ----
    k_gemm2<<<dim3(RB, 5), 256, 0, stream>>>(x, nullptr, w0h, w0l,
                                             nullptr, 0, xsb, linb, a,
                                             nullptr, N_NODES, 128, 520);
    k_agg<<<N_NODES, 256, 0, stream>>>(xsb, linb, a, rowptr, esrc, bg0, lb0, hb);
    k_bnstats<<<256, 256, 0, stream>>>(hb, bnsum0, bnsq0);
    k_bnapply<<<2048, 256, 0, stream>>>(hb, hpost, bnsum0, bnsq0, g0, b0);

    // ---- layer 1 (d = 256) ----
    k_gemm2<<<dim3(RB, 5), 256, 0, stream>>>(nullptr, hpost, w1h, w1l,
                                             nullptr, 0, xsb, linb, a,
                                             nullptr, N_NODES, 256, 520);
    k_agg<<<N_NODES, 256, 0, stream>>>(xsb, linb, a, rowptr, esrc, bg1, lb1, hb);
    k_bnstats<<<256, 256, 0, stream>>>(hb, bnsum1, bnsq1);
    k_bnapply<<<2048, 256, 0, stream>>>(hb, hpost, bnsum1, bnsq1, g1, b1);

    // ---- final FC ----
    k_gemm2<<<dim3(RB, 3), 256, 0, stream>>>(nullptr, hpost, fch, fcl,
                                             out, NCLS, nullptr, nullptr, nullptr,
                                             fcb, N_NODES, 256, NCLS);
}

// Round 8
// 627.962 us; speedup vs baseline: 1.2823x; 1.0837x over previous
//
#include <hip/hip_runtime.h>
#include <hip/hip_bf16.h>
#include <math.h>

#define N_NODES 50000
#define N_EDGES 800000
#define HCH 256      // H*HID concat width
#define NHEAD 4
#define HIDC 64
#define NCLS 349
#define F_IN 128

typedef short short8 __attribute__((ext_vector_type(8)));
typedef float floatx4 __attribute__((ext_vector_type(4)));

// ---------------- edge_index storage-width detection ----------------
__global__ void k_detect(const unsigned* ei, int* flag) {
    if (blockIdx.x == 0 && threadIdx.x == 0) {
        int i64 = 1;
        for (int e = 0; e < 64; e++)
            if (ei[2 * e + 1] != 0u) { i64 = 0; break; }
        *flag = i64;
    }
}

__device__ __forceinline__ void edge_sd(const int* ei, int e, int i64, int& s, int& d) {
    if (i64) {
        const long long* p = (const long long*)ei;
        s = (int)p[e]; d = (int)p[N_EDGES + e];
    } else {
        s = ei[e]; d = ei[N_EDGES + e];
    }
}

// ---------------- CSR build (by dst) ----------------
__global__ void k_deg(const int* ei, const int* flag, int* deg) {
    int e = blockIdx.x * 256 + threadIdx.x;
    if (e >= N_EDGES) return;
    int s, d; edge_sd(ei, e, *flag, s, d);
    atomicAdd(&deg[d], 1);
}

__global__ void k_scan(const int* __restrict__ deg, int* __restrict__ rowptr) {
    __shared__ int sums[1024];
    int t = threadIdx.x;
    const int CH = (N_NODES + 1023) / 1024;  // 49
    int beg = t * CH;
    int end = min(beg + CH, N_NODES);
    int s = 0;
    for (int i = beg; i < end; i++) s += deg[i];
    sums[t] = s;
    __syncthreads();
    for (int off = 1; off < 1024; off <<= 1) {
        int v = (t >= off) ? sums[t - off] : 0;
        __syncthreads();
        sums[t] += v;
        __syncthreads();
    }
    int excl = (t == 0) ? 0 : sums[t - 1];
    for (int i = beg; i < end; i++) { rowptr[i] = excl; excl += deg[i]; }
    if (t == 1023) rowptr[N_NODES] = sums[1023];
}

__global__ void k_fill(const int* ei, const int* flag, const int* __restrict__ rowptr,
                       int* cursor, int* __restrict__ esrc) {
    int e = blockIdx.x * 256 + threadIdx.x;
    if (e >= N_EDGES) return;
    int s, d; edge_sd(ei, e, *flag, s, d);
    int pos = atomicAdd(&cursor[d], 1);
    esrc[rowptr[d] + pos] = s;
}

// ---------------- attention-score folding ----------------
__global__ void k_wtilde(const float* __restrict__ ws, const float* __restrict__ wd,
                         const float* __restrict__ atts, const float* __restrict__ attd,
                         float* __restrict__ wt, int d) {
    int id = blockIdx.x * 256 + threadIdx.x;
    if (id >= d * 8) return;
    int j = id & 7, k = id >> 3;
    const float* w = (j < 4) ? ws : wd;
    const float* at = (j < 4) ? atts : attd;
    int h = j & 3;
    float s = 0.f;
    for (int c = 0; c < HIDC; c++) s += w[k * HCH + h * HIDC + c] * at[h * HIDC + c];
    wt[k * 8 + j] = s;
}

// ---------------- bf16 helpers ----------------
__device__ __forceinline__ unsigned short b16(float v) {
    __hip_bfloat16 t = __float2bfloat16(v);
    return *(unsigned short*)&t;
}

__device__ __forceinline__ float bfu(unsigned short u) {
    unsigned v = (unsigned)u << 16;
    return __builtin_bit_cast(float, v);
}

__device__ __forceinline__ void bsplit(float v, unsigned short& h, unsigned short& l) {
    __hip_bfloat16 bh = __float2bfloat16(v);
    float hv = __bfloat162float(bh);
    __hip_bfloat16 bl = __float2bfloat16(v - hv);
    h = *(unsigned short*)&bh;
    l = *(unsigned short*)&bl;
}

// fused weight, transposed+split: Bt[c][k], c in [0,640)
// c<256: ws col; c<512: lw col; c<520: wtilde col (attention); else 0 pad.
__global__ void k_wcat_t(const float* __restrict__ ws, const float* __restrict__ lw,
                         const float* __restrict__ wtil, int K,
                         unsigned short* __restrict__ Bh, unsigned short* __restrict__ Bl) {
    int id = blockIdx.x * 256 + threadIdx.x;
    if (id >= 640 * K) return;
    int c = id / K, k = id % K;
    float v;
    if (c < 256) v = ws[(size_t)k * 256 + c];
    else if (c < 512) v = lw[(size_t)k * 256 + (c - 256)];
    else if (c < 520) v = wtil[(size_t)k * 8 + (c - 512)];
    else v = 0.f;
    unsigned short h, l;
    bsplit(v, h, l);
    Bh[(size_t)c * K + k] = h;
    Bl[(size_t)c * K + k] = l;
}

// transposed+split fcw: Bt[384][256], pad cols (>=349) zeroed
__global__ void k_fcw_t(const float* __restrict__ fcw, int K,
                        unsigned short* __restrict__ Bh, unsigned short* __restrict__ Bl) {
    int id = blockIdx.x * 256 + threadIdx.x;
    if (id >= 384 * K) return;
    int c = id / K, k = id % K;
    float v = (c < NCLS) ? fcw[(size_t)k * NCLS + c] : 0.f;
    unsigned short h, l;
    bsplit(v, h, l);
    Bh[(size_t)c * K + k] = h;
    Bl[(size_t)c * K + k] = l;
}

// ---------------- 2-product MFMA GEMM: C ~= Ah*Bh + Ah*Bl ----------------
__global__ __launch_bounds__(256) void k_gemm2(
    const float* __restrict__ Af32, const __hip_bfloat16* __restrict__ Ab,
    const unsigned short* __restrict__ Bh, const unsigned short* __restrict__ Bl,
    float* __restrict__ C, int ldc, __hip_bfloat16* __restrict__ xsb,
    __hip_bfloat16* __restrict__ linbb, float* __restrict__ aout,
    const float* __restrict__ bias, int M, int K, int Nc) {
    __shared__ unsigned short sA[128 * 40];
    __shared__ unsigned short sBh[128 * 40];
    __shared__ unsigned short sBl[128 * 40];
    int tid = threadIdx.x;
    int lane = tid & 63, wave = tid >> 6;
    int wm = wave >> 1, wn = wave & 1;
    int row0 = blockIdx.x * 128, col0 = blockIdx.y * 128;
    floatx4 acc[4][4] = {};
    int sr = tid >> 1;
    int sc = (tid & 1) * 2;
    int kc = lane >> 4;
    int fr = lane & 15;
    for (int k0 = 0; k0 < K; k0 += 32) {
        int4 z = {0, 0, 0, 0};
        int4 va0 = z, va1 = z;
        int gr = row0 + sr;
        if (gr < M) {
            if (Af32) {
                const float* px = Af32 + (size_t)gr * K + k0 + sc * 8;
                float4 f0 = *(const float4*)(px);
                float4 f1 = *(const float4*)(px + 4);
                float4 f2 = *(const float4*)(px + 8);
                float4 f3 = *(const float4*)(px + 12);
                float xv[16] = {f0.x, f0.y, f0.z, f0.w, f1.x, f1.y, f1.z, f1.w,
                                f2.x, f2.y, f2.z, f2.w, f3.x, f3.y, f3.z, f3.w};
                union { unsigned short us[8]; int4 v; } u0, u1;
                #pragma unroll
                for (int q = 0; q < 8; q++) {
                    u0.us[q] = b16(xv[q]);
                    u1.us[q] = b16(xv[q + 8]);
                }
                va0 = u0.v; va1 = u1.v;
            } else {
                const __hip_bfloat16* pa = Ab + (size_t)gr * K + k0 + sc * 8;
                va0 = *(const int4*)(pa);
                va1 = *(const int4*)(pa + 8);
            }
        }
        *(int4*)((char*)sA + sr * 80 + sc * 16) = va0;
        *(int4*)((char*)sA + sr * 80 + sc * 16 + 16) = va1;
        const unsigned short* pb = Bh + (size_t)(col0 + sr) * K + k0 + sc * 8;
        const unsigned short* pbl = Bl + (size_t)(col0 + sr) * K + k0 + sc * 8;
        *(int4*)((char*)sBh + sr * 80 + sc * 16) = *(const int4*)(pb);
        *(int4*)((char*)sBh + sr * 80 + sc * 16 + 16) = *(const int4*)(pb + 8);
        *(int4*)((char*)sBl + sr * 80 + sc * 16) = *(const int4*)(pbl);
        *(int4*)((char*)sBl + sr * 80 + sc * 16 + 16) = *(const int4*)(pbl + 8);
        __syncthreads();
        short8 fah[4], fbh[4], fbl[4];
        #pragma unroll
        for (int i = 0; i < 4; i++) {
            int ar = wm * 64 + i * 16 + fr;
            fah[i] = *(const short8*)((const char*)sA + ar * 80 + kc * 16);
            int bc = wn * 64 + i * 16 + fr;
            fbh[i] = *(const short8*)((const char*)sBh + bc * 80 + kc * 16);
            fbl[i] = *(const short8*)((const char*)sBl + bc * 80 + kc * 16);
        }
        #pragma unroll
        for (int i = 0; i < 4; i++)
            #pragma unroll
            for (int j = 0; j < 4; j++) {
                acc[i][j] = __builtin_amdgcn_mfma_f32_16x16x32_bf16(fah[i], fbh[j], acc[i][j], 0, 0, 0);
                acc[i][j] = __builtin_amdgcn_mfma_f32_16x16x32_bf16(fah[i], fbl[j], acc[i][j], 0, 0, 0);
            }
        __syncthreads();
    }
    #pragma unroll
    for (int i = 0; i < 4; i++) {
        #pragma unroll
        for (int j = 0; j < 4; j++) {
            int c = col0 + wn * 64 + j * 16 + fr;
            if (c >= Nc) continue;
            float bv = bias ? bias[c] : 0.f;
            #pragma unroll
            for (int q = 0; q < 4; q++) {
                int r = row0 + wm * 64 + i * 16 + (lane >> 4) * 4 + q;
                if (r >= M) continue;
                float val = acc[i][j][q] + bv;
                if (C) C[(size_t)r * ldc + c] = val;
                else if (c < 256) xsb[(size_t)r * 256 + c] = __float2bfloat16(val);
                else if (c < 512) linbb[(size_t)r * 256 + (c - 256)] = __float2bfloat16(val);
                else aout[(size_t)r * 8 + (c - 512)] = val;
            }
        }
    }
}

// ---------------- fused CSR gather-aggregation ----------------
// R7: one WAVE per node, lane owns 4 channels (ushort4 = 8B/lane, full 512B
// message row in ONE wave-instruction). 8x unroll -> 4KB in flight per wave.
// No barriers, no shfl (R5/R6 lessons). ev recomputed per lane (cheap).
#define LEAKY_EXP(vv) __expf(((vv) > 0.f) ? (vv) : 0.2f * (vv))

__global__ __launch_bounds__(256) void k_agg(
    const __hip_bfloat16* __restrict__ xsb,
    const __hip_bfloat16* __restrict__ linb, const float* __restrict__ a,
    const int* __restrict__ rowptr, const int* __restrict__ esrc,
    const float* __restrict__ bg, const float* __restrict__ lb,
    __hip_bfloat16* __restrict__ hout) {
    int wave = threadIdx.x >> 6;
    int lane = threadIdx.x & 63;
    int n = blockIdx.x * 4 + wave;
    if (n >= N_NODES) return;
    int h = lane >> 4;          // head of this lane's 4 channels
    int c0 = lane * 4;          // first channel owned by this lane
    float ad = a[(size_t)n * 8 + 4 + h];
    int beg = rowptr[n], end = rowptr[n + 1];
    float a0 = 0.f, a1 = 0.f, a2 = 0.f, a3 = 0.f, dsum = 0.f;
    int k = beg;
    for (; k + 8 <= end; k += 8) {
        int s[8];
        #pragma unroll
        for (int u = 0; u < 8; u++) s[u] = esrc[k + u];
        ushort4 m[8];
        #pragma unroll
        for (int u = 0; u < 8; u++)
            m[u] = *(const ushort4*)(xsb + (size_t)s[u] * 256 + c0);
        float av[8];
        #pragma unroll
        for (int u = 0; u < 8; u++) av[u] = a[(size_t)s[u] * 8 + h];
        #pragma unroll
        for (int u = 0; u < 8; u++) {
            float ev = LEAKY_EXP(av[u] + ad);
            a0 += bfu(m[u].x) * ev;
            a1 += bfu(m[u].y) * ev;
            a2 += bfu(m[u].z) * ev;
            a3 += bfu(m[u].w) * ev;
            dsum += ev;
        }
    }
    for (; k < end; k++) {
        int s = esrc[k];
        ushort4 m = *(const ushort4*)(xsb + (size_t)s * 256 + c0);
        float ev = LEAKY_EXP(a[(size_t)s * 8 + h] + ad);
        a0 += bfu(m.x) * ev;
        a1 += bfu(m.y) * ev;
        a2 += bfu(m.z) * ev;
        a3 += bfu(m.w) * ev;
        dsum += ev;
    }
    float inv = 1.f / (dsum + 1e-16f);
    float4 bgv = *(const float4*)(bg + c0);
    float4 lbv = *(const float4*)(lb + c0);
    ushort4 lnv = *(const ushort4*)(linb + (size_t)n * 256 + c0);
    ushort4 o;
    o.x = b16(a0 * inv + bgv.x + bfu(lnv.x) + lbv.x);
    o.y = b16(a1 * inv + bgv.y + bfu(lnv.y) + lbv.y);
    o.z = b16(a2 * inv + bgv.z + bfu(lnv.z) + lbv.z);
    o.w = b16(a3 * inv + bgv.w + bfu(lnv.w) + lbv.w);
    *(ushort4*)(hout + (size_t)n * 256 + c0) = o;
}

// ---------------- BatchNorm (batch stats from bf16 h) ----------------
__global__ void k_bnstats(const __hip_bfloat16* __restrict__ hb,
                          float* __restrict__ bnsum, float* __restrict__ bnsq) {
    int c = threadIdx.x;
    float s = 0.f, q = 0.f;
    for (int r = blockIdx.x; r < N_NODES; r += gridDim.x) {
        float v = __bfloat162float(hb[(size_t)r * 256 + c]);
        s += v; q += v * v;
    }
    atomicAdd(&bnsum[c], s);
    atomicAdd(&bnsq[c], q);
}

// BN finalize (per-block redundant) + affine + ReLU -> bf16 hpost.
__global__ __launch_bounds__(256) void k_bnapply(
    const __hip_bfloat16* __restrict__ hb, __hip_bfloat16* __restrict__ hpost,
    const float* __restrict__ bnsum, const float* __restrict__ bnsq,
    const float* __restrict__ g, const float* __restrict__ b) {
    __shared__ float sA[256], sB[256];
    int t = threadIdx.x;
    {
        float m = bnsum[t] / (float)N_NODES;
        float v = bnsq[t] / (float)N_NODES - m * m;
        float rs = rsqrtf(v + 1e-5f) * g[t];
        sA[t] = rs;
        sB[t] = b[t] - m * rs;
    }
    __syncthreads();
    size_t tot = (size_t)N_NODES * 256;
    for (size_t i = (size_t)blockIdx.x * 256 + t; i < tot;
         i += (size_t)gridDim.x * 256) {
        int c = (int)(i & 255);
        float v = __bfloat162float(hb[i]) * sA[c] + sB[c];
        v = v > 0.f ? v : 0.f;
        hpost[i] = __float2bfloat16(v);
    }
}

// ---------------- host ----------------
extern "C" void kernel_launch(void* const* d_in, const int* in_sizes, int n_in,
                              void* d_out, int out_size, void* d_ws, size_t ws_size,
                              hipStream_t stream) {
    const float* x     = (const float*)d_in[0];
    const int*   ei    = (const int*)d_in[1];
    const float* ws0   = (const float*)d_in[2];
    const float* wd0   = (const float*)d_in[3];
    const float* atts0 = (const float*)d_in[4];
    const float* attd0 = (const float*)d_in[5];
    const float* bg0   = (const float*)d_in[6];
    const float* lw0   = (const float*)d_in[7];
    const float* lb0   = (const float*)d_in[8];
    const float* g0    = (const float*)d_in[9];
    const float* b0    = (const float*)d_in[10];
    const float* ws1   = (const float*)d_in[11];
    const float* wd1   = (const float*)d_in[12];
    const float* atts1 = (const float*)d_in[13];
    const float* attd1 = (const float*)d_in[14];
    const float* bg1   = (const float*)d_in[15];
    const float* lw1   = (const float*)d_in[16];
    const float* lb1   = (const float*)d_in[17];
    const float* g1    = (const float*)d_in[18];
    const float* b1    = (const float*)d_in[19];
    const float* fcw   = (const float*)d_in[20];
    const float* fcb   = (const float*)d_in[21];
    float* out = (float*)d_out;

    char* p = (char*)d_ws;
    auto alloc = [&](size_t bytes) -> char* {
        char* r = p;
        p += (bytes + 255) & ~(size_t)255;
        return r;
    };
    __hip_bfloat16* xsb   = (__hip_bfloat16*)alloc((size_t)N_NODES * 256 * 2);
    __hip_bfloat16* linb  = (__hip_bfloat16*)alloc((size_t)N_NODES * 256 * 2);
    __hip_bfloat16* hb    = (__hip_bfloat16*)alloc((size_t)N_NODES * 256 * 2);
    __hip_bfloat16* hpost = (__hip_bfloat16*)alloc((size_t)N_NODES * 256 * 2);
    float* a      = (float*)alloc((size_t)N_NODES * 8 * 4);
    int*   esrc   = (int*)alloc((size_t)N_EDGES * 4);
    int*   rowptr = (int*)alloc((size_t)(N_NODES + 1) * 4);
    unsigned short* w0h = (unsigned short*)alloc((size_t)640 * 128 * 2);
    unsigned short* w0l = (unsigned short*)alloc((size_t)640 * 128 * 2);
    unsigned short* w1h = (unsigned short*)alloc((size_t)640 * 256 * 2);
    unsigned short* w1l = (unsigned short*)alloc((size_t)640 * 256 * 2);
    unsigned short* fch = (unsigned short*)alloc((size_t)384 * 256 * 2);
    unsigned short* fcl = (unsigned short*)alloc((size_t)384 * 256 * 2);
    float* wtil   = (float*)alloc((size_t)256 * 8 * 4);
    int*   flag   = (int*)alloc(256);
    size_t zr_bytes = (size_t)N_NODES * 4 * 2 + 4 * 256 * 4;
    char* zbase = alloc(zr_bytes);
    int*   deg    = (int*)zbase;
    int*   cursor = deg + N_NODES;
    float* bnsum0 = (float*)(cursor + N_NODES);
    float* bnsq0  = bnsum0 + 256;
    float* bnsum1 = bnsq0 + 256;
    float* bnsq1  = bnsum1 + 256;

    hipMemsetAsync(zbase, 0, zr_bytes, stream);

    const int EB = (N_EDGES + 255) / 256;
    const int RB = (N_NODES + 127) / 128;
    const int AB = (N_NODES + 3) / 4;   // k_agg blocks: 4 nodes (waves) each

    k_detect<<<1, 1, 0, stream>>>((const unsigned*)ei, flag);
    k_deg<<<EB, 256, 0, stream>>>(ei, flag, deg);
    k_scan<<<1, 1024, 0, stream>>>(deg, rowptr);
    k_fill<<<EB, 256, 0, stream>>>(ei, flag, rowptr, cursor, esrc);

    // weight prep (wtil buffer reused sequentially; stream is serial)
    k_wtilde<<<(128 * 8 + 255) / 256, 256, 0, stream>>>(ws0, wd0, atts0, attd0, wtil, 128);
    k_wcat_t<<<(640 * 128 + 255) / 256, 256, 0, stream>>>(ws0, lw0, wtil, 128, w0h, w0l);
    k_wtilde<<<(256 * 8 + 255) / 256, 256, 0, stream>>>(ws1, wd1, atts1, attd1, wtil, 256);
    k_wcat_t<<<(640 * 256 + 255) / 256, 256, 0, stream>>>(ws1, lw1, wtil, 256, w1h, w1l);
    k_fcw_t<<<(384 * 256 + 255) / 256, 256, 0, stream>>>(fcw, 256, fch, fcl);

    // ---- layer 0 (d = 128): gemm emits xs(bf16) | lin(bf16) | attention a ----
    k_gemm2<<<dim3(RB, 5), 256, 0, stream>>>(x, nullptr, w0h, w0l,
                                             nullptr, 0, xsb, linb, a,
                                             nullptr, N_NODES, 128, 520);
    k_agg<<<AB, 256, 0, stream>>>(xsb, linb, a, rowptr, esrc, bg0, lb0, hb);
    k_bnstats<<<256, 256, 0, stream>>>(hb, bnsum0, bnsq0);
    k_bnapply<<<2048, 256, 0, stream>>>(hb, hpost, bnsum0, bnsq0, g0, b0);

    // ---- layer 1 (d = 256) ----
    k_gemm2<<<dim3(RB, 5), 256, 0, stream>>>(nullptr, hpost, w1h, w1l,
                                             nullptr, 0, xsb, linb, a,
                                             nullptr, N_NODES, 256, 520);
    k_agg<<<AB, 256, 0, stream>>>(xsb, linb, a, rowptr, esrc, bg1, lb1, hb);
    k_bnstats<<<256, 256, 0, stream>>>(hb, bnsum1, bnsq1);
    k_bnapply<<<2048, 256, 0, stream>>>(hb, hpost, bnsum1, bnsq1, g1, b1);

    // ---- final FC ----
    k_gemm2<<<dim3(RB, 3), 256, 0, stream>>>(nullptr, hpost, fch, fcl,
                                             out, NCLS, nullptr, nullptr, nullptr,
                                             fcb, N_NODES, 256, NCLS);
}

// Round 9
// 559.771 us; speedup vs baseline: 1.4385x; 1.1218x over previous
//
#include <hip/hip_runtime.h>
#include <hip/hip_bf16.h>
#include <math.h>

#define N_NODES 50000
#define N_EDGES 800000
#define HCH 256      // H*HID concat width
#define NHEAD 4
#define HIDC 64
#define NCLS 349
#define F_IN 128

typedef short short8 __attribute__((ext_vector_type(8)));
typedef float floatx4 __attribute__((ext_vector_type(4)));

// ---------------- edge_index storage-width detection ----------------
__global__ void k_detect(const unsigned* ei, int* flag) {
    if (blockIdx.x == 0 && threadIdx.x == 0) {
        int i64 = 1;
        for (int e = 0; e < 64; e++)
            if (ei[2 * e + 1] != 0u) { i64 = 0; break; }
        *flag = i64;
    }
}

__device__ __forceinline__ void edge_sd(const int* ei, int e, int i64, int& s, int& d) {
    if (i64) {
        const long long* p = (const long long*)ei;
        s = (int)p[e]; d = (int)p[N_EDGES + e];
    } else {
        s = ei[e]; d = ei[N_EDGES + e];
    }
}

// ---------------- CSR build (by dst) ----------------
__global__ void k_deg(const int* ei, const int* flag, int* deg) {
    int e = blockIdx.x * 256 + threadIdx.x;
    if (e >= N_EDGES) return;
    int s, d; edge_sd(ei, e, *flag, s, d);
    atomicAdd(&deg[d], 1);
}

// hierarchical scan, stage 1: 1024 elements/block, block-local exclusive scan
__global__ __launch_bounds__(256) void k_scan1(const int* __restrict__ deg,
                                               int* __restrict__ rowptr,
                                               int* __restrict__ bsum) {
    __shared__ int sd[256];
    int t = threadIdx.x;
    int base = blockIdx.x * 1024 + t * 4;
    int d0 = 0, d1 = 0, d2 = 0, d3 = 0;
    if (base + 3 < N_NODES) {
        int4 v = *(const int4*)(deg + base);
        d0 = v.x; d1 = v.y; d2 = v.z; d3 = v.w;
    } else {
        if (base + 0 < N_NODES) d0 = deg[base + 0];
        if (base + 1 < N_NODES) d1 = deg[base + 1];
        if (base + 2 < N_NODES) d2 = deg[base + 2];
        if (base + 3 < N_NODES) d3 = deg[base + 3];
    }
    int ts = d0 + d1 + d2 + d3;
    sd[t] = ts;
    __syncthreads();
    // Hillis-Steele inclusive scan over 256 thread sums
    #pragma unroll
    for (int off = 1; off < 256; off <<= 1) {
        int v = (t >= off) ? sd[t - off] : 0;
        __syncthreads();
        sd[t] += v;
        __syncthreads();
    }
    int excl = (t == 0) ? 0 : sd[t - 1];
    if (base + 0 < N_NODES) rowptr[base + 0] = excl;
    if (base + 1 < N_NODES) rowptr[base + 1] = excl + d0;
    if (base + 2 < N_NODES) rowptr[base + 2] = excl + d0 + d1;
    if (base + 3 < N_NODES) rowptr[base + 3] = excl + d0 + d1 + d2;
    if (t == 255) bsum[blockIdx.x] = sd[255];
}

// stage 2: one wave scans the block sums (nb <= 64)
__global__ void k_scan2(int* __restrict__ bsum, int nb, int* __restrict__ rowptr) {
    int lane = threadIdx.x;
    int orig = (lane < nb) ? bsum[lane] : 0;
    int v = orig;
    #pragma unroll
    for (int off = 1; off < 64; off <<= 1) {
        int tv = __shfl_up(v, off, 64);
        if (lane >= off) v += tv;
    }
    if (lane < nb) bsum[lane] = v - orig;   // exclusive
    if (lane == 0) rowptr[N_NODES] = N_EDGES;
}

// stage 3: add block offsets
__global__ __launch_bounds__(256) void k_scan3(int* __restrict__ rowptr,
                                               const int* __restrict__ bsum) {
    int base = blockIdx.x * 1024 + threadIdx.x * 4;
    int off = bsum[blockIdx.x];
    if (base + 3 < N_NODES) {
        int4 v = *(int4*)(rowptr + base);
        v.x += off; v.y += off; v.z += off; v.w += off;
        *(int4*)(rowptr + base) = v;
    } else {
        for (int j = 0; j < 4; j++)
            if (base + j < N_NODES) rowptr[base + j] += off;
    }
}

__global__ void k_fill(const int* ei, const int* flag, const int* __restrict__ rowptr,
                       int* cursor, int* __restrict__ esrc) {
    int e = blockIdx.x * 256 + threadIdx.x;
    if (e >= N_EDGES) return;
    int s, d; edge_sd(ei, e, *flag, s, d);
    int pos = atomicAdd(&cursor[d], 1);
    esrc[rowptr[d] + pos] = s;
}

// ---------------- attention-score folding ----------------
__global__ void k_wtilde(const float* __restrict__ ws, const float* __restrict__ wd,
                         const float* __restrict__ atts, const float* __restrict__ attd,
                         float* __restrict__ wt, int d) {
    int id = blockIdx.x * 256 + threadIdx.x;
    if (id >= d * 8) return;
    int j = id & 7, k = id >> 3;
    const float* w = (j < 4) ? ws : wd;
    const float* at = (j < 4) ? atts : attd;
    int h = j & 3;
    float s = 0.f;
    for (int c = 0; c < HIDC; c++) s += w[k * HCH + h * HIDC + c] * at[h * HIDC + c];
    wt[k * 8 + j] = s;
}

// ---------------- bf16 helpers ----------------
__device__ __forceinline__ unsigned short b16(float v) {
    __hip_bfloat16 t = __float2bfloat16(v);
    return *(unsigned short*)&t;
}

__device__ __forceinline__ float bfu(unsigned short u) {
    unsigned v = (unsigned)u << 16;
    return __builtin_bit_cast(float, v);
}

__device__ __forceinline__ void bsplit(float v, unsigned short& h, unsigned short& l) {
    __hip_bfloat16 bh = __float2bfloat16(v);
    float hv = __bfloat162float(bh);
    __hip_bfloat16 bl = __float2bfloat16(v - hv);
    h = *(unsigned short*)&bh;
    l = *(unsigned short*)&bl;
}

// fused weight, transposed+split: Bt[c][k], c in [0,640)
// c<256: ws col; c<512: lw col; c<520: wtilde col (attention); else 0 pad.
__global__ void k_wcat_t(const float* __restrict__ ws, const float* __restrict__ lw,
                         const float* __restrict__ wtil, int K,
                         unsigned short* __restrict__ Bh, unsigned short* __restrict__ Bl) {
    int id = blockIdx.x * 256 + threadIdx.x;
    if (id >= 640 * K) return;
    int c = id / K, k = id % K;
    float v;
    if (c < 256) v = ws[(size_t)k * 256 + c];
    else if (c < 512) v = lw[(size_t)k * 256 + (c - 256)];
    else if (c < 520) v = wtil[(size_t)k * 8 + (c - 512)];
    else v = 0.f;
    unsigned short h, l;
    bsplit(v, h, l);
    Bh[(size_t)c * K + k] = h;
    Bl[(size_t)c * K + k] = l;
}

// transposed+split fcw: Bt[384][256], pad cols (>=349) zeroed
__global__ void k_fcw_t(const float* __restrict__ fcw, int K,
                        unsigned short* __restrict__ Bh, unsigned short* __restrict__ Bl) {
    int id = blockIdx.x * 256 + threadIdx.x;
    if (id >= 384 * K) return;
    int c = id / K, k = id % K;
    float v = (c < NCLS) ? fcw[(size_t)k * NCLS + c] : 0.f;
    unsigned short h, l;
    bsplit(v, h, l);
    Bh[(size_t)c * K + k] = h;
    Bl[(size_t)c * K + k] = l;
}

// ---------------- 2-product MFMA GEMM: C ~= Ah*Bh + Ah*Bl ----------------
__global__ __launch_bounds__(256) void k_gemm2(
    const float* __restrict__ Af32, const __hip_bfloat16* __restrict__ Ab,
    const unsigned short* __restrict__ Bh, const unsigned short* __restrict__ Bl,
    float* __restrict__ C, int ldc, __hip_bfloat16* __restrict__ xsb,
    __hip_bfloat16* __restrict__ linbb, float* __restrict__ aout,
    const float* __restrict__ bias, int M, int K, int Nc) {
    __shared__ unsigned short sA[128 * 40];
    __shared__ unsigned short sBh[128 * 40];
    __shared__ unsigned short sBl[128 * 40];
    int tid = threadIdx.x;
    int lane = tid & 63, wave = tid >> 6;
    int wm = wave >> 1, wn = wave & 1;
    int row0 = blockIdx.x * 128, col0 = blockIdx.y * 128;
    floatx4 acc[4][4] = {};
    int sr = tid >> 1;
    int sc = (tid & 1) * 2;
    int kc = lane >> 4;
    int fr = lane & 15;
    for (int k0 = 0; k0 < K; k0 += 32) {
        int4 z = {0, 0, 0, 0};
        int4 va0 = z, va1 = z;
        int gr = row0 + sr;
        if (gr < M) {
            if (Af32) {
                const float* px = Af32 + (size_t)gr * K + k0 + sc * 8;
                float4 f0 = *(const float4*)(px);
                float4 f1 = *(const float4*)(px + 4);
                float4 f2 = *(const float4*)(px + 8);
                float4 f3 = *(const float4*)(px + 12);
                float xv[16] = {f0.x, f0.y, f0.z, f0.w, f1.x, f1.y, f1.z, f1.w,
                                f2.x, f2.y, f2.z, f2.w, f3.x, f3.y, f3.z, f3.w};
                union { unsigned short us[8]; int4 v; } u0, u1;
                #pragma unroll
                for (int q = 0; q < 8; q++) {
                    u0.us[q] = b16(xv[q]);
                    u1.us[q] = b16(xv[q + 8]);
                }
                va0 = u0.v; va1 = u1.v;
            } else {
                const __hip_bfloat16* pa = Ab + (size_t)gr * K + k0 + sc * 8;
                va0 = *(const int4*)(pa);
                va1 = *(const int4*)(pa + 8);
            }
        }
        *(int4*)((char*)sA + sr * 80 + sc * 16) = va0;
        *(int4*)((char*)sA + sr * 80 + sc * 16 + 16) = va1;
        const unsigned short* pb = Bh + (size_t)(col0 + sr) * K + k0 + sc * 8;
        const unsigned short* pbl = Bl + (size_t)(col0 + sr) * K + k0 + sc * 8;
        *(int4*)((char*)sBh + sr * 80 + sc * 16) = *(const int4*)(pb);
        *(int4*)((char*)sBh + sr * 80 + sc * 16 + 16) = *(const int4*)(pb + 8);
        *(int4*)((char*)sBl + sr * 80 + sc * 16) = *(const int4*)(pbl);
        *(int4*)((char*)sBl + sr * 80 + sc * 16 + 16) = *(const int4*)(pbl + 8);
        __syncthreads();
        short8 fah[4], fbh[4], fbl[4];
        #pragma unroll
        for (int i = 0; i < 4; i++) {
            int ar = wm * 64 + i * 16 + fr;
            fah[i] = *(const short8*)((const char*)sA + ar * 80 + kc * 16);
            int bc = wn * 64 + i * 16 + fr;
            fbh[i] = *(const short8*)((const char*)sBh + bc * 80 + kc * 16);
            fbl[i] = *(const short8*)((const char*)sBl + bc * 80 + kc * 16);
        }
        #pragma unroll
        for (int i = 0; i < 4; i++)
            #pragma unroll
            for (int j = 0; j < 4; j++) {
                acc[i][j] = __builtin_amdgcn_mfma_f32_16x16x32_bf16(fah[i], fbh[j], acc[i][j], 0, 0, 0);
                acc[i][j] = __builtin_amdgcn_mfma_f32_16x16x32_bf16(fah[i], fbl[j], acc[i][j], 0, 0, 0);
            }
        __syncthreads();
    }
    #pragma unroll
    for (int i = 0; i < 4; i++) {
        #pragma unroll
        for (int j = 0; j < 4; j++) {
            int c = col0 + wn * 64 + j * 16 + fr;
            if (c >= Nc) continue;
            float bv = bias ? bias[c] : 0.f;
            #pragma unroll
            for (int q = 0; q < 4; q++) {
                int r = row0 + wm * 64 + i * 16 + (lane >> 4) * 4 + q;
                if (r >= M) continue;
                float val = acc[i][j][q] + bv;
                if (C) C[(size_t)r * ldc + c] = val;
                else if (c < 256) xsb[(size_t)r * 256 + c] = __float2bfloat16(val);
                else if (c < 512) linbb[(size_t)r * 256 + (c - 256)] = __float2bfloat16(val);
                else aout[(size_t)r * 8 + (c - 512)] = val;
            }
        }
    }
}

// ---------------- fused CSR gather-aggregation (R7 wave-per-node) ----------------
#define LEAKY_EXP(vv) __expf(((vv) > 0.f) ? (vv) : 0.2f * (vv))

__global__ __launch_bounds__(256) void k_agg(
    const __hip_bfloat16* __restrict__ xsb,
    const __hip_bfloat16* __restrict__ linb, const float* __restrict__ a,
    const int* __restrict__ rowptr, const int* __restrict__ esrc,
    const float* __restrict__ bg, const float* __restrict__ lb,
    __hip_bfloat16* __restrict__ hout) {
    int wave = threadIdx.x >> 6;
    int lane = threadIdx.x & 63;
    int n = blockIdx.x * 4 + wave;
    if (n >= N_NODES) return;
    int h = lane >> 4;          // head of this lane's 4 channels
    int c0 = lane * 4;          // first channel owned by this lane
    float ad = a[(size_t)n * 8 + 4 + h];
    int beg = rowptr[n], end = rowptr[n + 1];
    float a0 = 0.f, a1 = 0.f, a2 = 0.f, a3 = 0.f, dsum = 0.f;
    int k = beg;
    for (; k + 8 <= end; k += 8) {
        int s[8];
        #pragma unroll
        for (int u = 0; u < 8; u++) s[u] = esrc[k + u];
        ushort4 m[8];
        #pragma unroll
        for (int u = 0; u < 8; u++)
            m[u] = *(const ushort4*)(xsb + (size_t)s[u] * 256 + c0);
        float av[8];
        #pragma unroll
        for (int u = 0; u < 8; u++) av[u] = a[(size_t)s[u] * 8 + h];
        #pragma unroll
        for (int u = 0; u < 8; u++) {
            float ev = LEAKY_EXP(av[u] + ad);
            a0 += bfu(m[u].x) * ev;
            a1 += bfu(m[u].y) * ev;
            a2 += bfu(m[u].z) * ev;
            a3 += bfu(m[u].w) * ev;
            dsum += ev;
        }
    }
    for (; k < end; k++) {
        int s = esrc[k];
        ushort4 m = *(const ushort4*)(xsb + (size_t)s * 256 + c0);
        float ev = LEAKY_EXP(a[(size_t)s * 8 + h] + ad);
        a0 += bfu(m.x) * ev;
        a1 += bfu(m.y) * ev;
        a2 += bfu(m.z) * ev;
        a3 += bfu(m.w) * ev;
        dsum += ev;
    }
    float inv = 1.f / (dsum + 1e-16f);
    float4 bgv = *(const float4*)(bg + c0);
    float4 lbv = *(const float4*)(lb + c0);
    ushort4 lnv = *(const ushort4*)(linb + (size_t)n * 256 + c0);
    ushort4 o;
    o.x = b16(a0 * inv + bgv.x + bfu(lnv.x) + lbv.x);
    o.y = b16(a1 * inv + bgv.y + bfu(lnv.y) + lbv.y);
    o.z = b16(a2 * inv + bgv.z + bfu(lnv.z) + lbv.z);
    o.w = b16(a3 * inv + bgv.w + bfu(lnv.w) + lbv.w);
    *(ushort4*)(hout + (size_t)n * 256 + c0) = o;
}

// ---------------- BatchNorm (batch stats from bf16 h) ----------------
__global__ void k_bnstats(const __hip_bfloat16* __restrict__ hb,
                          float* __restrict__ bnsum, float* __restrict__ bnsq) {
    int c = threadIdx.x;
    float s = 0.f, q = 0.f;
    for (int r = blockIdx.x; r < N_NODES; r += gridDim.x) {
        float v = __bfloat162float(hb[(size_t)r * 256 + c]);
        s += v; q += v * v;
    }
    atomicAdd(&bnsum[c], s);
    atomicAdd(&bnsq[c], q);
}

// BN finalize (per-block redundant) + affine + ReLU -> bf16 hpost.
__global__ __launch_bounds__(256) void k_bnapply(
    const __hip_bfloat16* __restrict__ hb, __hip_bfloat16* __restrict__ hpost,
    const float* __restrict__ bnsum, const float* __restrict__ bnsq,
    const float* __restrict__ g, const float* __restrict__ b) {
    __shared__ float sA[256], sB[256];
    int t = threadIdx.x;
    {
        float m = bnsum[t] / (float)N_NODES;
        float v = bnsq[t] / (float)N_NODES - m * m;
        float rs = rsqrtf(v + 1e-5f) * g[t];
        sA[t] = rs;
        sB[t] = b[t] - m * rs;
    }
    __syncthreads();
    size_t tot = (size_t)N_NODES * 256;
    for (size_t i = (size_t)blockIdx.x * 256 + t; i < tot;
         i += (size_t)gridDim.x * 256) {
        int c = (int)(i & 255);
        float v = __bfloat162float(hb[i]) * sA[c] + sB[c];
        v = v > 0.f ? v : 0.f;
        hpost[i] = __float2bfloat16(v);
    }
}

// ---------------- host ----------------
extern "C" void kernel_launch(void* const* d_in, const int* in_sizes, int n_in,
                              void* d_out, int out_size, void* d_ws, size_t ws_size,
                              hipStream_t stream) {
    const float* x     = (const float*)d_in[0];
    const int*   ei    = (const int*)d_in[1];
    const float* ws0   = (const float*)d_in[2];
    const float* wd0   = (const float*)d_in[3];
    const float* atts0 = (const float*)d_in[4];
    const float* attd0 = (const float*)d_in[5];
    const float* bg0   = (const float*)d_in[6];
    const float* lw0   = (const float*)d_in[7];
    const float* lb0   = (const float*)d_in[8];
    const float* g0    = (const float*)d_in[9];
    const float* b0    = (const float*)d_in[10];
    const float* ws1   = (const float*)d_in[11];
    const float* wd1   = (const float*)d_in[12];
    const float* atts1 = (const float*)d_in[13];
    const float* attd1 = (const float*)d_in[14];
    const float* bg1   = (const float*)d_in[15];
    const float* lw1   = (const float*)d_in[16];
    const float* lb1   = (const float*)d_in[17];
    const float* g1    = (const float*)d_in[18];
    const float* b1    = (const float*)d_in[19];
    const float* fcw   = (const float*)d_in[20];
    const float* fcb   = (const float*)d_in[21];
    float* out = (float*)d_out;

    char* p = (char*)d_ws;
    auto alloc = [&](size_t bytes) -> char* {
        char* r = p;
        p += (bytes + 255) & ~(size_t)255;
        return r;
    };
    __hip_bfloat16* xsb   = (__hip_bfloat16*)alloc((size_t)N_NODES * 256 * 2);
    __hip_bfloat16* linb  = (__hip_bfloat16*)alloc((size_t)N_NODES * 256 * 2);
    __hip_bfloat16* hb    = (__hip_bfloat16*)alloc((size_t)N_NODES * 256 * 2);
    __hip_bfloat16* hpost = (__hip_bfloat16*)alloc((size_t)N_NODES * 256 * 2);
    float* a      = (float*)alloc((size_t)N_NODES * 8 * 4);
    int*   esrc   = (int*)alloc((size_t)N_EDGES * 4);
    int*   rowptr = (int*)alloc((size_t)(N_NODES + 1) * 4);
    int*   bsum   = (int*)alloc(64 * 4);
    unsigned short* w0h = (unsigned short*)alloc((size_t)640 * 128 * 2);
    unsigned short* w0l = (unsigned short*)alloc((size_t)640 * 128 * 2);
    unsigned short* w1h = (unsigned short*)alloc((size_t)640 * 256 * 2);
    unsigned short* w1l = (unsigned short*)alloc((size_t)640 * 256 * 2);
    unsigned short* fch = (unsigned short*)alloc((size_t)384 * 256 * 2);
    unsigned short* fcl = (unsigned short*)alloc((size_t)384 * 256 * 2);
    float* wtil   = (float*)alloc((size_t)256 * 8 * 4);
    int*   flag   = (int*)alloc(256);
    size_t zr_bytes = (size_t)N_NODES * 4 * 2 + 4 * 256 * 4;
    char* zbase = alloc(zr_bytes);
    int*   deg    = (int*)zbase;
    int*   cursor = deg + N_NODES;
    float* bnsum0 = (float*)(cursor + N_NODES);
    float* bnsq0  = bnsum0 + 256;
    float* bnsum1 = bnsq0 + 256;
    float* bnsq1  = bnsum1 + 256;

    hipMemsetAsync(zbase, 0, zr_bytes, stream);

    const int EB = (N_EDGES + 255) / 256;
    const int RB = (N_NODES + 127) / 128;
    const int AB = (N_NODES + 3) / 4;          // k_agg blocks: 4 nodes (waves) each
    const int SB = (N_NODES + 1023) / 1024;    // scan blocks: 49

    k_detect<<<1, 1, 0, stream>>>((const unsigned*)ei, flag);
    k_deg<<<EB, 256, 0, stream>>>(ei, flag, deg);
    k_scan1<<<SB, 256, 0, stream>>>(deg, rowptr, bsum);
    k_scan2<<<1, 64, 0, stream>>>(bsum, SB, rowptr);
    k_scan3<<<SB, 256, 0, stream>>>(rowptr, bsum);
    k_fill<<<EB, 256, 0, stream>>>(ei, flag, rowptr, cursor, esrc);

    // weight prep (wtil buffer reused sequentially; stream is serial)
    k_wtilde<<<(128 * 8 + 255) / 256, 256, 0, stream>>>(ws0, wd0, atts0, attd0, wtil, 128);
    k_wcat_t<<<(640 * 128 + 255) / 256, 256, 0, stream>>>(ws0, lw0, wtil, 128, w0h, w0l);
    k_wtilde<<<(256 * 8 + 255) / 256, 256, 0, stream>>>(ws1, wd1, atts1, attd1, wtil, 256);
    k_wcat_t<<<(640 * 256 + 255) / 256, 256, 0, stream>>>(ws1, lw1, wtil, 256, w1h, w1l);
    k_fcw_t<<<(384 * 256 + 255) / 256, 256, 0, stream>>>(fcw, 256, fch, fcl);

    // ---- layer 0 (d = 128): gemm emits xs(bf16) | lin(bf16) | attention a ----
    k_gemm2<<<dim3(RB, 5), 256, 0, stream>>>(x, nullptr, w0h, w0l,
                                             nullptr, 0, xsb, linb, a,
                                             nullptr, N_NODES, 128, 520);
    k_agg<<<AB, 256, 0, stream>>>(xsb, linb, a, rowptr, esrc, bg0, lb0, hb);
    k_bnstats<<<256, 256, 0, stream>>>(hb, bnsum0, bnsq0);
    k_bnapply<<<2048, 256, 0, stream>>>(hb, hpost, bnsum0, bnsq0, g0, b0);

    // ---- layer 1 (d = 256) ----
    k_gemm2<<<dim3(RB, 5), 256, 0, stream>>>(nullptr, hpost, w1h, w1l,
                                             nullptr, 0, xsb, linb, a,
                                             nullptr, N_NODES, 256, 520);
    k_agg<<<AB, 256, 0, stream>>>(xsb, linb, a, rowptr, esrc, bg1, lb1, hb);
    k_bnstats<<<256, 256, 0, stream>>>(hb, bnsum1, bnsq1);
    k_bnapply<<<2048, 256, 0, stream>>>(hb, hpost, bnsum1, bnsq1, g1, b1);

    // ---- final FC ----
    k_gemm2<<<dim3(RB, 3), 256, 0, stream>>>(nullptr, hpost, fch, fcl,
                                             out, NCLS, nullptr, nullptr, nullptr,
                                             fcb, N_NODES, 256, NCLS);
}

// Round 10
// 545.847 us; speedup vs baseline: 1.4752x; 1.0255x over previous
//
#include <hip/hip_runtime.h>
#include <hip/hip_bf16.h>
#include <math.h>

#define N_NODES 50000
#define MPAD 50048      // padded row count for GEMM A-tiles (128-multiple)
#define N_EDGES 800000
#define HCH 256
#define NHEAD 4
#define HIDC 64
#define NCLS 349
#define F_IN 128

typedef short short8 __attribute__((ext_vector_type(8)));
typedef float floatx4 __attribute__((ext_vector_type(4)));

// ---------------- edge_index storage-width detection ----------------
__global__ void k_detect(const unsigned* ei, int* flag) {
    if (blockIdx.x == 0 && threadIdx.x == 0) {
        int i64 = 1;
        for (int e = 0; e < 64; e++)
            if (ei[2 * e + 1] != 0u) { i64 = 0; break; }
        *flag = i64;
    }
}

__device__ __forceinline__ void edge_sd(const int* ei, int e, int i64, int& s, int& d) {
    if (i64) {
        const long long* p = (const long long*)ei;
        s = (int)p[e]; d = (int)p[N_EDGES + e];
    } else {
        s = ei[e]; d = ei[N_EDGES + e];
    }
}

// ---------------- CSR build (by dst) ----------------
__global__ void k_deg(const int* ei, const int* flag, int* deg) {
    int e = blockIdx.x * 256 + threadIdx.x;
    if (e >= N_EDGES) return;
    int s, d; edge_sd(ei, e, *flag, s, d);
    atomicAdd(&deg[d], 1);
}

__global__ __launch_bounds__(256) void k_scan1(const int* __restrict__ deg,
                                               int* __restrict__ rowptr,
                                               int* __restrict__ bsum) {
    __shared__ int sd[256];
    int t = threadIdx.x;
    int base = blockIdx.x * 1024 + t * 4;
    int d0 = 0, d1 = 0, d2 = 0, d3 = 0;
    if (base + 3 < N_NODES) {
        int4 v = *(const int4*)(deg + base);
        d0 = v.x; d1 = v.y; d2 = v.z; d3 = v.w;
    } else {
        if (base + 0 < N_NODES) d0 = deg[base + 0];
        if (base + 1 < N_NODES) d1 = deg[base + 1];
        if (base + 2 < N_NODES) d2 = deg[base + 2];
        if (base + 3 < N_NODES) d3 = deg[base + 3];
    }
    int ts = d0 + d1 + d2 + d3;
    sd[t] = ts;
    __syncthreads();
    #pragma unroll
    for (int off = 1; off < 256; off <<= 1) {
        int v = (t >= off) ? sd[t - off] : 0;
        __syncthreads();
        sd[t] += v;
        __syncthreads();
    }
    int excl = (t == 0) ? 0 : sd[t - 1];
    if (base + 0 < N_NODES) rowptr[base + 0] = excl;
    if (base + 1 < N_NODES) rowptr[base + 1] = excl + d0;
    if (base + 2 < N_NODES) rowptr[base + 2] = excl + d0 + d1;
    if (base + 3 < N_NODES) rowptr[base + 3] = excl + d0 + d1 + d2;
    if (t == 255) bsum[blockIdx.x] = sd[255];
}

__global__ void k_scan2(int* __restrict__ bsum, int nb, int* __restrict__ rowptr) {
    int lane = threadIdx.x;
    int orig = (lane < nb) ? bsum[lane] : 0;
    int v = orig;
    #pragma unroll
    for (int off = 1; off < 64; off <<= 1) {
        int tv = __shfl_up(v, off, 64);
        if (lane >= off) v += tv;
    }
    if (lane < nb) bsum[lane] = v - orig;
    if (lane == 0) rowptr[N_NODES] = N_EDGES;
}

__global__ __launch_bounds__(256) void k_scan3(int* __restrict__ rowptr,
                                               const int* __restrict__ bsum) {
    int base = blockIdx.x * 1024 + threadIdx.x * 4;
    int off = bsum[blockIdx.x];
    if (base + 3 < N_NODES) {
        int4 v = *(int4*)(rowptr + base);
        v.x += off; v.y += off; v.z += off; v.w += off;
        *(int4*)(rowptr + base) = v;
    } else {
        for (int j = 0; j < 4; j++)
            if (base + j < N_NODES) rowptr[base + j] += off;
    }
}

__global__ void k_fill(const int* ei, const int* flag, const int* __restrict__ rowptr,
                       int* cursor, int* __restrict__ esrc) {
    int e = blockIdx.x * 256 + threadIdx.x;
    if (e >= N_EDGES) return;
    int s, d; edge_sd(ei, e, *flag, s, d);
    int pos = atomicAdd(&cursor[d], 1);
    esrc[rowptr[d] + pos] = s;
}

// ---------------- attention-score folding ----------------
__global__ void k_wtilde(const float* __restrict__ ws, const float* __restrict__ wd,
                         const float* __restrict__ atts, const float* __restrict__ attd,
                         float* __restrict__ wt, int d) {
    int id = blockIdx.x * 256 + threadIdx.x;
    if (id >= d * 8) return;
    int j = id & 7, k = id >> 3;
    const float* w = (j < 4) ? ws : wd;
    const float* at = (j < 4) ? atts : attd;
    int h = j & 3;
    float s = 0.f;
    for (int c = 0; c < HIDC; c++) s += w[k * HCH + h * HIDC + c] * at[h * HIDC + c];
    wt[k * 8 + j] = s;
}

// ---------------- bf16 helpers ----------------
__device__ __forceinline__ unsigned short b16(float v) {
    __hip_bfloat16 t = __float2bfloat16(v);
    return *(unsigned short*)&t;
}

__device__ __forceinline__ float bfu(unsigned short u) {
    unsigned v = (unsigned)u << 16;
    return __builtin_bit_cast(float, v);
}

__device__ __forceinline__ void bsplit(float v, unsigned short& h, unsigned short& l) {
    __hip_bfloat16 bh = __float2bfloat16(v);
    float hv = __bfloat162float(bh);
    __hip_bfloat16 bl = __float2bfloat16(v - hv);
    h = *(unsigned short*)&bh;
    l = *(unsigned short*)&bl;
}

// x f32 -> bf16 (same rounding the old GEMM staging applied; pad rows left as-is)
__global__ __launch_bounds__(256) void k_xcast(const float* __restrict__ x,
                                               unsigned short* __restrict__ xb) {
    size_t tot = (size_t)N_NODES * 128 / 4;
    for (size_t i = (size_t)blockIdx.x * 256 + threadIdx.x; i < tot;
         i += (size_t)gridDim.x * 256) {
        float4 v = *(const float4*)(x + i * 4);
        ushort4 o = {b16(v.x), b16(v.y), b16(v.z), b16(v.w)};
        *(ushort4*)(xb + i * 4) = o;
    }
}

// fused weight, transposed+split: Bt[c][k], c in [0,640)
__global__ void k_wcat_t(const float* __restrict__ ws, const float* __restrict__ lw,
                         const float* __restrict__ wtil, int K,
                         unsigned short* __restrict__ Bh, unsigned short* __restrict__ Bl) {
    int id = blockIdx.x * 256 + threadIdx.x;
    if (id >= 640 * K) return;
    int c = id / K, k = id % K;
    float v;
    if (c < 256) v = ws[(size_t)k * 256 + c];
    else if (c < 512) v = lw[(size_t)k * 256 + (c - 256)];
    else if (c < 520) v = wtil[(size_t)k * 8 + (c - 512)];
    else v = 0.f;
    unsigned short h, l;
    bsplit(v, h, l);
    Bh[(size_t)c * K + k] = h;
    Bl[(size_t)c * K + k] = l;
}

__global__ void k_fcw_t(const float* __restrict__ fcw, int K,
                        unsigned short* __restrict__ Bh, unsigned short* __restrict__ Bl) {
    int id = blockIdx.x * 256 + threadIdx.x;
    if (id >= 384 * K) return;
    int c = id / K, k = id % K;
    float v = (c < NCLS) ? fcw[(size_t)k * NCLS + c] : 0.f;
    unsigned short h, l;
    bsplit(v, h, l);
    Bh[(size_t)c * K + k] = h;
    Bl[(size_t)c * K + k] = l;
}

// ---------------- global_load_lds helper (16B per lane, wave-linear dest) ----
__device__ __forceinline__ void gload16(const void* g, void* l) {
    __builtin_amdgcn_global_load_lds(
        (const __attribute__((address_space(1))) void*)g,
        (__attribute__((address_space(3))) void*)l, 16, 0, 0);
}

// ---------------- m97-style 2-product MFMA GEMM ----------------
// C ~= A*Bh + A*Bl. A: bf16 [MPAD][K]; Bh/Bl: bf16 [NcPad][K].
// Staging: global_load_lds dwordx4, LDS linear 8KB/tile; bank swizzle realized
// by per-lane SOURCE addressing (inverse of read swizzle):
//   physical 16B slot of (row,kc) = line*8 + (((row&1)*4+kc) ^ (line&7)), line=row>>1
// Reads use the same mapping -> every bank-quad serves exactly 2 lanes (free).
__global__ __launch_bounds__(256) void k_gemm2(
    const unsigned short* __restrict__ Ab,
    const unsigned short* __restrict__ Bh, const unsigned short* __restrict__ Bl,
    float* __restrict__ C, int ldc, __hip_bfloat16* __restrict__ xsb,
    __hip_bfloat16* __restrict__ linbb, float* __restrict__ aout,
    const float* __restrict__ bias, int M, int K, int Nc) {
    __shared__ unsigned short sA[4096];    // 8KB: 128 rows x 32 k
    __shared__ unsigned short sBh[4096];
    __shared__ unsigned short sBl[4096];
    int tid = threadIdx.x;
    int lane = tid & 63, wave = tid >> 6;
    int wm = wave >> 1, wn = wave & 1;
    int row0 = blockIdx.x * 128, col0 = blockIdx.y * 128;

    // staging source (row, kc) for this lane, for the 2 instrs per tile
    int rowq[2], kcq[2];
    #pragma unroll
    for (int q = 0; q < 2; q++) {
        int lds16 = wave * 128 + q * 64 + lane;   // 16B-slot index in tile
        int line = lds16 >> 3;
        int slot0 = (lds16 & 7) ^ (line & 7);     // unswizzle
        rowq[q] = (line << 1) | (slot0 >> 2);
        kcq[q] = slot0 & 3;
    }
    // fragment read byte-offsets (swizzled), k-invariant
    int kc = lane >> 4, fr = lane & 15;
    int offA[4], offB[4];
    #pragma unroll
    for (int i = 0; i < 4; i++) {
        int ar = wm * 64 + i * 16 + fr;
        int ln = ar >> 1;
        int sl = (((ar & 1) << 2) | kc) ^ (ln & 7);
        offA[i] = ln * 128 + sl * 16;
        int bc = wn * 64 + i * 16 + fr;
        ln = bc >> 1;
        sl = (((bc & 1) << 2) | kc) ^ (ln & 7);
        offB[i] = ln * 128 + sl * 16;
    }

    floatx4 acc[4][4] = {};
    for (int k0 = 0; k0 < K; k0 += 32) {
        #pragma unroll
        for (int q = 0; q < 2; q++) {
            int lb = wave * 2048 + q * 1024;
            gload16(Ab + (size_t)(row0 + rowq[q]) * K + k0 + kcq[q] * 8, (char*)sA + lb);
            gload16(Bh + (size_t)(col0 + rowq[q]) * K + k0 + kcq[q] * 8, (char*)sBh + lb);
            gload16(Bl + (size_t)(col0 + rowq[q]) * K + k0 + kcq[q] * 8, (char*)sBl + lb);
        }
        __syncthreads();   // compiler emits vmcnt(0) drain before barrier
        short8 fah[4], fbh[4], fbl[4];
        #pragma unroll
        for (int i = 0; i < 4; i++) {
            fah[i] = *(const short8*)((const char*)sA + offA[i]);
            fbh[i] = *(const short8*)((const char*)sBh + offB[i]);
            fbl[i] = *(const short8*)((const char*)sBl + offB[i]);
        }
        #pragma unroll
        for (int i = 0; i < 4; i++)
            #pragma unroll
            for (int j = 0; j < 4; j++) {
                acc[i][j] = __builtin_amdgcn_mfma_f32_16x16x32_bf16(fah[i], fbh[j], acc[i][j], 0, 0, 0);
                acc[i][j] = __builtin_amdgcn_mfma_f32_16x16x32_bf16(fah[i], fbl[j], acc[i][j], 0, 0, 0);
            }
        __syncthreads();
    }
    #pragma unroll
    for (int i = 0; i < 4; i++) {
        #pragma unroll
        for (int j = 0; j < 4; j++) {
            int c = col0 + wn * 64 + j * 16 + fr;
            if (c >= Nc) continue;
            float bv = bias ? bias[c] : 0.f;
            #pragma unroll
            for (int q = 0; q < 4; q++) {
                int r = row0 + wm * 64 + i * 16 + (lane >> 4) * 4 + q;
                if (r >= M) continue;
                float val = acc[i][j][q] + bv;
                if (C) C[(size_t)r * ldc + c] = val;
                else if (c < 256) xsb[(size_t)r * 256 + c] = __float2bfloat16(val);
                else if (c < 512) linbb[(size_t)r * 256 + (c - 256)] = __float2bfloat16(val);
                else aout[(size_t)r * 8 + (c - 512)] = val;
            }
        }
    }
}

// ---------------- fused CSR gather-aggregation (R7 wave-per-node) ----------------
#define LEAKY_EXP(vv) __expf(((vv) > 0.f) ? (vv) : 0.2f * (vv))

__global__ __launch_bounds__(256) void k_agg(
    const __hip_bfloat16* __restrict__ xsb,
    const __hip_bfloat16* __restrict__ linb, const float* __restrict__ a,
    const int* __restrict__ rowptr, const int* __restrict__ esrc,
    const float* __restrict__ bg, const float* __restrict__ lb,
    __hip_bfloat16* __restrict__ hout) {
    int wave = threadIdx.x >> 6;
    int lane = threadIdx.x & 63;
    int n = blockIdx.x * 4 + wave;
    if (n >= N_NODES) return;
    int h = lane >> 4;
    int c0 = lane * 4;
    float ad = a[(size_t)n * 8 + 4 + h];
    int beg = rowptr[n], end = rowptr[n + 1];
    float a0 = 0.f, a1 = 0.f, a2 = 0.f, a3 = 0.f, dsum = 0.f;
    int k = beg;
    for (; k + 8 <= end; k += 8) {
        int s[8];
        #pragma unroll
        for (int u = 0; u < 8; u++) s[u] = esrc[k + u];
        ushort4 m[8];
        #pragma unroll
        for (int u = 0; u < 8; u++)
            m[u] = *(const ushort4*)(xsb + (size_t)s[u] * 256 + c0);
        float av[8];
        #pragma unroll
        for (int u = 0; u < 8; u++) av[u] = a[(size_t)s[u] * 8 + h];
        #pragma unroll
        for (int u = 0; u < 8; u++) {
            float ev = LEAKY_EXP(av[u] + ad);
            a0 += bfu(m[u].x) * ev;
            a1 += bfu(m[u].y) * ev;
            a2 += bfu(m[u].z) * ev;
            a3 += bfu(m[u].w) * ev;
            dsum += ev;
        }
    }
    for (; k < end; k++) {
        int s = esrc[k];
        ushort4 m = *(const ushort4*)(xsb + (size_t)s * 256 + c0);
        float ev = LEAKY_EXP(a[(size_t)s * 8 + h] + ad);
        a0 += bfu(m.x) * ev;
        a1 += bfu(m.y) * ev;
        a2 += bfu(m.z) * ev;
        a3 += bfu(m.w) * ev;
        dsum += ev;
    }
    float inv = 1.f / (dsum + 1e-16f);
    float4 bgv = *(const float4*)(bg + c0);
    float4 lbv = *(const float4*)(lb + c0);
    ushort4 lnv = *(const ushort4*)(linb + (size_t)n * 256 + c0);
    ushort4 o;
    o.x = b16(a0 * inv + bgv.x + bfu(lnv.x) + lbv.x);
    o.y = b16(a1 * inv + bgv.y + bfu(lnv.y) + lbv.y);
    o.z = b16(a2 * inv + bgv.z + bfu(lnv.z) + lbv.z);
    o.w = b16(a3 * inv + bgv.w + bfu(lnv.w) + lbv.w);
    *(ushort4*)(hout + (size_t)n * 256 + c0) = o;
}

// ---------------- BatchNorm ----------------
__global__ void k_bnstats(const __hip_bfloat16* __restrict__ hb,
                          float* __restrict__ bnsum, float* __restrict__ bnsq) {
    int c = threadIdx.x;
    float s = 0.f, q = 0.f;
    for (int r = blockIdx.x; r < N_NODES; r += gridDim.x) {
        float v = __bfloat162float(hb[(size_t)r * 256 + c]);
        s += v; q += v * v;
    }
    atomicAdd(&bnsum[c], s);
    atomicAdd(&bnsq[c], q);
}

__global__ __launch_bounds__(256) void k_bnapply(
    const __hip_bfloat16* __restrict__ hb, __hip_bfloat16* __restrict__ hpost,
    const float* __restrict__ bnsum, const float* __restrict__ bnsq,
    const float* __restrict__ g, const float* __restrict__ b) {
    __shared__ float sA[256], sB[256];
    int t = threadIdx.x;
    {
        float m = bnsum[t] / (float)N_NODES;
        float v = bnsq[t] / (float)N_NODES - m * m;
        float rs = rsqrtf(v + 1e-5f) * g[t];
        sA[t] = rs;
        sB[t] = b[t] - m * rs;
    }
    __syncthreads();
    size_t tot = (size_t)N_NODES * 256;
    for (size_t i = (size_t)blockIdx.x * 256 + t; i < tot;
         i += (size_t)gridDim.x * 256) {
        int c = (int)(i & 255);
        float v = __bfloat162float(hb[i]) * sA[c] + sB[c];
        v = v > 0.f ? v : 0.f;
        hpost[i] = __float2bfloat16(v);
    }
}

// ---------------- host ----------------
extern "C" void kernel_launch(void* const* d_in, const int* in_sizes, int n_in,
                              void* d_out, int out_size, void* d_ws, size_t ws_size,
                              hipStream_t stream) {
    const float* x     = (const float*)d_in[0];
    const int*   ei    = (const int*)d_in[1];
    const float* ws0   = (const float*)d_in[2];
    const float* wd0   = (const float*)d_in[3];
    const float* atts0 = (const float*)d_in[4];
    const float* attd0 = (const float*)d_in[5];
    const float* bg0   = (const float*)d_in[6];
    const float* lw0   = (const float*)d_in[7];
    const float* lb0   = (const float*)d_in[8];
    const float* g0    = (const float*)d_in[9];
    const float* b0    = (const float*)d_in[10];
    const float* ws1   = (const float*)d_in[11];
    const float* wd1   = (const float*)d_in[12];
    const float* atts1 = (const float*)d_in[13];
    const float* attd1 = (const float*)d_in[14];
    const float* bg1   = (const float*)d_in[15];
    const float* lw1   = (const float*)d_in[16];
    const float* lb1   = (const float*)d_in[17];
    const float* g1    = (const float*)d_in[18];
    const float* b1    = (const float*)d_in[19];
    const float* fcw   = (const float*)d_in[20];
    const float* fcb   = (const float*)d_in[21];
    float* out = (float*)d_out;

    char* p = (char*)d_ws;
    auto alloc = [&](size_t bytes) -> char* {
        char* r = p;
        p += (bytes + 255) & ~(size_t)255;
        return r;
    };
    __hip_bfloat16* xsb   = (__hip_bfloat16*)alloc((size_t)N_NODES * 256 * 2);
    __hip_bfloat16* linb  = (__hip_bfloat16*)alloc((size_t)N_NODES * 256 * 2);
    __hip_bfloat16* hb    = (__hip_bfloat16*)alloc((size_t)N_NODES * 256 * 2);
    __hip_bfloat16* hpost = (__hip_bfloat16*)alloc((size_t)MPAD * 256 * 2);   // padded A
    unsigned short* xb    = (unsigned short*)alloc((size_t)MPAD * 128 * 2);   // padded A
    float* a      = (float*)alloc((size_t)N_NODES * 8 * 4);
    int*   esrc   = (int*)alloc((size_t)N_EDGES * 4);
    int*   rowptr = (int*)alloc((size_t)(N_NODES + 1) * 4);
    int*   bsum   = (int*)alloc(64 * 4);
    unsigned short* w0h = (unsigned short*)alloc((size_t)640 * 128 * 2);
    unsigned short* w0l = (unsigned short*)alloc((size_t)640 * 128 * 2);
    unsigned short* w1h = (unsigned short*)alloc((size_t)640 * 256 * 2);
    unsigned short* w1l = (unsigned short*)alloc((size_t)640 * 256 * 2);
    unsigned short* fch = (unsigned short*)alloc((size_t)384 * 256 * 2);
    unsigned short* fcl = (unsigned short*)alloc((size_t)384 * 256 * 2);
    float* wtil   = (float*)alloc((size_t)256 * 8 * 4);
    int*   flag   = (int*)alloc(256);
    size_t zr_bytes = (size_t)N_NODES * 4 * 2 + 4 * 256 * 4;
    char* zbase = alloc(zr_bytes);
    int*   deg    = (int*)zbase;
    int*   cursor = deg + N_NODES;
    float* bnsum0 = (float*)(cursor + N_NODES);
    float* bnsq0  = bnsum0 + 256;
    float* bnsum1 = bnsq0 + 256;
    float* bnsq1  = bnsum1 + 256;

    hipMemsetAsync(zbase, 0, zr_bytes, stream);

    const int EB = (N_EDGES + 255) / 256;
    const int RB = MPAD / 128;                 // 391
    const int AB = (N_NODES + 3) / 4;
    const int SB = (N_NODES + 1023) / 1024;    // 49

    k_detect<<<1, 1, 0, stream>>>((const unsigned*)ei, flag);
    k_deg<<<EB, 256, 0, stream>>>(ei, flag, deg);
    k_scan1<<<SB, 256, 0, stream>>>(deg, rowptr, bsum);
    k_scan2<<<1, 64, 0, stream>>>(bsum, SB, rowptr);
    k_scan3<<<SB, 256, 0, stream>>>(rowptr, bsum);
    k_fill<<<EB, 256, 0, stream>>>(ei, flag, rowptr, cursor, esrc);

    // weight prep
    k_wtilde<<<(128 * 8 + 255) / 256, 256, 0, stream>>>(ws0, wd0, atts0, attd0, wtil, 128);
    k_wcat_t<<<(640 * 128 + 255) / 256, 256, 0, stream>>>(ws0, lw0, wtil, 128, w0h, w0l);
    k_wtilde<<<(256 * 8 + 255) / 256, 256, 0, stream>>>(ws1, wd1, atts1, attd1, wtil, 256);
    k_wcat_t<<<(640 * 256 + 255) / 256, 256, 0, stream>>>(ws1, lw1, wtil, 256, w1h, w1l);
    k_fcw_t<<<(384 * 256 + 255) / 256, 256, 0, stream>>>(fcw, 256, fch, fcl);
    k_xcast<<<2048, 256, 0, stream>>>(x, xb);

    // ---- layer 0 (d = 128) ----
    k_gemm2<<<dim3(RB, 5), 256, 0, stream>>>(xb, w0h, w0l,
                                             nullptr, 0, xsb, linb, a,
                                             nullptr, N_NODES, 128, 520);
    k_agg<<<AB, 256, 0, stream>>>(xsb, linb, a, rowptr, esrc, bg0, lb0, hb);
    k_bnstats<<<256, 256, 0, stream>>>(hb, bnsum0, bnsq0);
    k_bnapply<<<2048, 256, 0, stream>>>(hb, hpost, bnsum0, bnsq0, g0, b0);

    // ---- layer 1 (d = 256) ----
    k_gemm2<<<dim3(RB, 5), 256, 0, stream>>>((const unsigned short*)hpost, w1h, w1l,
                                             nullptr, 0, xsb, linb, a,
                                             nullptr, N_NODES, 256, 520);
    k_agg<<<AB, 256, 0, stream>>>(xsb, linb, a, rowptr, esrc, bg1, lb1, hb);
    k_bnstats<<<256, 256, 0, stream>>>(hb, bnsum1, bnsq1);
    k_bnapply<<<2048, 256, 0, stream>>>(hb, hpost, bnsum1, bnsq1, g1, b1);

    // ---- final FC ----
    k_gemm2<<<dim3(RB, 3), 256, 0, stream>>>((const unsigned short*)hpost, fch, fcl,
                                             out, NCLS, nullptr, nullptr, nullptr,
                                             fcb, N_NODES, 256, NCLS);
}